// Round 5
// baseline (1422.269 us; speedup 1.0000x reference)
//
#include <hip/hip_runtime.h>
#include <hip/hip_cooperative_groups.h>

namespace cg = cooperative_groups;

#define NAPP  100000
#define NATTR 50000
#define NE    500000
#define D     128
#define NTOT  (NATTR + 2 * NAPP)
#define SCHUNK 1024
#define SNB   ((NTOT + SCHUNK - 1) / SCHUNK)
#define GB_APP  ((NAPP + 63) / 64)
#define GB_ATTR ((NATTR + 63) / 64)
#define BUILD_GRID 1024

typedef __attribute__((ext_vector_type(8))) short bfrag;
typedef __attribute__((ext_vector_type(4))) float f32x4;

__device__ __forceinline__ short bf16_rn(float x) {
    union { float f; unsigned u; } a; a.f = x;
    unsigned r = (a.u + 0x7fffu + ((a.u >> 16) & 1u)) >> 16;
    return (short)r;
}
__device__ __forceinline__ float bf16_to_f(short s) {
    union { float f; unsigned u; } a;
    a.u = ((unsigned)(unsigned short)s) << 16;
    return a.f;
}

// split two floats into packed bf16-hi pair and bf16-lo (residual) pair.
__device__ __forceinline__ void split2(float x, float y, unsigned& hw, unsigned& lw) {
    union { float f; unsigned u; } ax, ay;
    ax.f = x; ay.f = y;
    unsigned hx = (ax.u + 0x7fffu + ((ax.u >> 16) & 1u)) >> 16;
    unsigned hy = (ay.u + 0x7fffu + ((ay.u >> 16) & 1u)) >> 16;
    union { unsigned u; float f; } fx, fy;
    fx.u = hx << 16; fy.u = hy << 16;
    union { float f; unsigned u; } rx, ry;
    rx.f = x - fx.f; ry.f = y - fy.f;
    unsigned lx = (rx.u + 0x7fffu + ((rx.u >> 16) & 1u)) >> 16;
    unsigned ly = (ry.u + 0x7fffu + ((ry.u >> 16) & 1u)) >> 16;
    hw = (hy << 16) | (hx & 0xffffu);
    lw = (ly << 16) | (lx & 0xffffu);
}

// ================= cooperative build: zero+pack | hist | scan | scatter ======
struct BuildArgs {
    const int *s0, *d0; const float* e0;
    const int *s1, *d1; const float* e1;
    const int *s2, *d2; const float* e2;
    const float *Wself1, *Wneigh1, *Wself2, *Wneigh2, *b1, *b2, *Wc, *bc;
    short *PBh, *PBl;
    float *b1s, *b2s, *Cs, *C1, *C2, *bconst;
    int *cur, *rp0, *rp1, *rp2, *bsum, *boff;
    int2 *cw0, *cw1, *cw2;
};

__global__ __launch_bounds__(256) void build_all_kernel(BuildArgs a) {
    cg::grid_group grid = cg::this_grid();
    __shared__ int sd[256];
    const int t = threadIdx.x;
    const int gtid = blockIdx.x * 256 + t;
    const int gstride = BUILD_GRID * 256;
    int* cur0 = a.cur;
    int* cur1 = cur0 + NATTR;
    int* cur2 = cur1 + NAPP;

    // ---- phase 0: blocks 0..8 pack weights/constants; blocks 9.. zero cur ----
    if (blockIdx.x < 9) {
        int m = blockIdx.x;
        if (m == 8) {
            int k = t >> 1, j = t & 1;
            const float* Wn1 = a.Wneigh2 + D * D;
            const float* Wn2 = a.Wneigh2 + 2 * D * D;
            const float* Ws1 = a.Wself2 + D * D;
            const float* Ws2 = a.Wself2 + 2 * D * D;
            float ss = 0.f, s1 = 0.f, s2 = 0.f;
            for (int tt = 0; tt < D; tt++) {
                float wc = a.Wc[tt * 2 + j];
                ss += (Ws1[k * D + tt] + Ws2[k * D + tt]) * wc;
                s1 += Wn1[k * D + tt] * wc;
                s2 += Wn2[k * D + tt] * wc;
            }
            a.Cs[t] = ss; a.C1[t] = s1; a.C2[t] = s2;
            if (t < 2) {
                float s = a.bc[t];
                for (int tt = 0; tt < D; tt++)
                    s += (a.b2[D + tt] + a.b2[2 * D + tt]) * a.Wc[tt * 2 + t];
                a.bconst[t] = s;
            }
        } else {
            const float* srcA; const float* srcB = nullptr;
            switch (m) {
                case 0: srcA = a.Wself1; break;
                case 1: srcA = a.Wneigh1; break;
                case 2: srcA = a.Wself1 + D * D; srcB = a.Wself1 + 2 * D * D; break;
                case 3: srcA = a.Wneigh1 + D * D; break;
                case 4: srcA = a.Wneigh1 + 2 * D * D; break;
                case 5: srcA = a.Wself2 + D * D; srcB = a.Wself2 + 2 * D * D; break;
                case 6: srcA = a.Wneigh2 + D * D; break;
                default: srcA = a.Wneigh2 + 2 * D * D; break;
            }
            short* oh = a.PBh + (size_t)m * D * D;
            short* ol = a.PBl + (size_t)m * D * D;
            for (int i = t; i < D * D; i += 256) {
                int k = i >> 7, n = i & 127;
                float v = srcA[i];
                if (srcB) v += srcB[i];
                short hi = bf16_rn(v);
                short lo = bf16_rn(v - bf16_to_f(hi));
                int kc = k >> 5, q = (k >> 3) & 3, j = k & 7, nt = n >> 4, c = n & 15;
                int pos = (((kc * 8 + nt) * 64) + q * 16 + c) * 8 + j;
                oh[pos] = hi;
                ol[pos] = lo;
            }
            if (m == 0 && t < D) {
                a.b1s[t] = a.b1[D + t] + a.b1[2 * D + t];
                a.b2s[t] = a.b2[D + t] + a.b2[2 * D + t];
            }
        }
    } else {
        int idx = (blockIdx.x - 9) * 256 + t;
        const int n4 = (SNB * SCHUNK) / 4;
        for (int i = idx; i < n4; i += (BUILD_GRID - 9) * 256)
            *(int4*)(a.cur + i * 4) = make_int4(0, 0, 0, 0);
    }
    __threadfence();
    grid.sync();

    // ---- phase 1: histogram over 3 relations ----
    for (int i = gtid; i < NE; i += gstride) atomicAdd(&cur0[a.d0[i]], 1);
    for (int i = gtid; i < NE; i += gstride) atomicAdd(&cur1[a.d1[i]], 1);
    for (int i = gtid; i < NE; i += gstride) atomicAdd(&cur2[a.d2[i]], 1);
    __threadfence();
    grid.sync();

    // ---- phase 2: per-chunk partial sums ----
    if (blockIdx.x < SNB) {
        int b = blockIdx.x;
        int4 v = *((const int4*)(a.cur + b * SCHUNK) + t);
        int s = v.x + v.y + v.z + v.w;
        sd[t] = s;
        __syncthreads();
        for (int off = 128; off > 0; off >>= 1) {
            if (t < off) sd[t] += sd[t + off];
            __syncthreads();
        }
        if (t == 0) a.bsum[b] = sd[0];
    }
    __threadfence();
    grid.sync();

    // ---- phase 3: chunk-offset scan (block 0) ----
    if (blockIdx.x == 0) {
        int v = (t < SNB) ? a.bsum[t] : 0;
        sd[t] = v;
        __syncthreads();
        for (int off = 1; off < 256; off <<= 1) {
            int u = (t >= off) ? sd[t - off] : 0;
            __syncthreads();
            sd[t] += u;
            __syncthreads();
        }
        a.boff[t] = sd[t] - v;
        if (t == 0) { a.rp0[NATTR] = NE; a.rp1[NAPP] = NE; a.rp2[NAPP] = NE; }
    }
    __threadfence();
    grid.sync();

    // ---- phase 4: final scan -> row pointers + running cursors ----
    if (blockIdx.x < SNB) {
        int b = blockIdx.x;
        int base = b * SCHUNK + t * 4;
        int4 v = *(const int4*)(a.cur + base);
        int s = v.x + v.y + v.z + v.w;
        sd[t] = s;
        __syncthreads();
        for (int off = 1; off < 256; off <<= 1) {
            int u = (t >= off) ? sd[t - off] : 0;
            __syncthreads();
            sd[t] += u;
            __syncthreads();
        }
        int pre = a.boff[b] + sd[t] - s;
        int ex[4];
        ex[0] = pre;
        ex[1] = ex[0] + v.x;
        ex[2] = ex[1] + v.y;
        ex[3] = ex[2] + v.z;
        #pragma unroll
        for (int i = 0; i < 4; i++) {
            int idx = base + i;
            if (idx < NTOT) {
                int* rp; int loc; int rbase;
                if (idx < NATTR)             { rp = a.rp0; loc = idx;                 rbase = 0; }
                else if (idx < NATTR + NAPP) { rp = a.rp1; loc = idx - NATTR;        rbase = NE; }
                else                         { rp = a.rp2; loc = idx - NATTR - NAPP; rbase = 2 * NE; }
                int val = ex[i] - rbase;
                rp[loc] = val;
                a.cur[idx] = val;
            }
        }
    }
    __threadfence();
    grid.sync();

    // ---- phase 5: scatter (src, ew) into CSR slots ----
    for (int i = gtid; i < NE; i += gstride) {
        int p = atomicAdd(&cur0[a.d0[i]], 1);
        int2 v; v.x = a.s0[i]; v.y = __float_as_int(a.e0[i]);
        a.cw0[p] = v;
    }
    for (int i = gtid; i < NE; i += gstride) {
        int p = atomicAdd(&cur1[a.d1[i]], 1);
        int2 v; v.x = a.s1[i]; v.y = __float_as_int(a.e1[i]);
        a.cw1[p] = v;
    }
    for (int i = gtid; i < NE; i += gstride) {
        int p = atomicAdd(&cur2[a.d2[i]], 1);
        int2 v; v.x = a.s2[i]; v.y = __float_as_int(a.e2[i]);
        a.cw2[p] = v;
    }
}

// ---------------- fused gather + MFMA node update + collapsed classifier ----
// Gather restructured quad-row x 4-edge: per 32-lane group, 4 rows advance in
// lockstep per iteration (16 cw + 16 x-row loads in flight vs 8 before),
// halving the number of sequential memory-wait steps. Per-row FMA statement
// shape/order unchanged (clamped edges add exact +0.0f) -> bitwise identical.
#define ASTR 128
#define ACC4(dst, b) \
    dst.x += wt[b] * v[b].x + wt[b+1] * v[b+1].x + wt[b+2] * v[b+2].x + wt[b+3] * v[b+3].x; \
    dst.y += wt[b] * v[b].y + wt[b+1] * v[b+1].y + wt[b+2] * v[b+2].y + wt[b+3] * v[b+3].y; \
    dst.z += wt[b] * v[b].z + wt[b+1] * v[b+1].z + wt[b+2] * v[b+2].z + wt[b+3] * v[b+3].z; \
    dst.w += wt[b] * v[b].w + wt[b+1] * v[b+1].w + wt[b+2] * v[b+2].w + wt[b+3] * v[b+3].w;

template<int NG>
__device__ __forceinline__ void fused_body(
        const float* __restrict__ in0, const short* __restrict__ B0h, const short* __restrict__ B0l,
        const float* __restrict__ x1, const int* __restrict__ rp1, const int2* __restrict__ cw1,
        const short* __restrict__ B1h, const short* __restrict__ B1l,
        const float* __restrict__ x2, const int* __restrict__ rp2, const int2* __restrict__ cw2,
        const short* __restrict__ B2h, const short* __restrict__ B2l,
        const float* __restrict__ bias,
        const float* __restrict__ Ccol0, const float* __restrict__ Ccol1,
        float* __restrict__ zo0, float* __restrict__ zo1,
        int nrows, int row0, float* At) {
    const int t = threadIdx.x;
    const int w = t >> 6, lane = t & 63;
    const int q = lane >> 4, c = lane & 15;
    const int myrow = row0 + w * 16 + c;
    const int arow = min(myrow, nrows - 1);

    f32x4 acc[8];
    #pragma unroll
    for (int nt = 0; nt < 8; nt++) acc[nt] = (f32x4){0.f, 0.f, 0.f, 0.f};

    // ---- direct (self) source: global -> reg fragments ----
    {
        const float* __restrict__ arp = in0 + (size_t)arow * D;
        const bfrag* __restrict__ Bh = (const bfrag*)B0h;
        const bfrag* __restrict__ Bl = (const bfrag*)B0l;
        #pragma unroll
        for (int kc = 0; kc < 4; kc++) {
            float4 a0 = *(const float4*)(arp + kc * 32 + q * 8);
            float4 a1 = *(const float4*)(arp + kc * 32 + q * 8 + 4);
            union { unsigned u[4]; bfrag v; } ahu, alu;
            split2(a0.x, a0.y, ahu.u[0], alu.u[0]);
            split2(a0.z, a0.w, ahu.u[1], alu.u[1]);
            split2(a1.x, a1.y, ahu.u[2], alu.u[2]);
            split2(a1.z, a1.w, ahu.u[3], alu.u[3]);
            bfrag ah = ahu.v, al = alu.v;
            const bfrag* bh = Bh + kc * 512 + lane;
            const bfrag* bl = Bl + kc * 512 + lane;
            #pragma unroll
            for (int nt = 0; nt < 8; nt++) {
                bfrag vh = bh[nt * 64];
                bfrag vl = bl[nt * 64];
                acc[nt] = __builtin_amdgcn_mfma_f32_16x16x32_bf16(ah, vh, acc[nt], 0, 0, 0);
                acc[nt] = __builtin_amdgcn_mfma_f32_16x16x32_bf16(ah, vl, acc[nt], 0, 0, 0);
                acc[nt] = __builtin_amdgcn_mfma_f32_16x16x32_bf16(al, vh, acc[nt], 0, 0, 0);
            }
        }
    }

    // ---- gathered sources: cooperative gather -> LDS -> MFMA ----
    const int grp = t >> 5, l32 = t & 31;
    #pragma unroll
    for (int g = 0; g < NG; g++) {
        const float* __restrict__ xs = (g == 0) ? x1 : x2;
        const int* __restrict__ rp   = (g == 0) ? rp1 : rp2;
        const int2* __restrict__ cw  = (g == 0) ? cw1 : cw2;
        const short* __restrict__ Bhp = (g == 0) ? B1h : B2h;
        const short* __restrict__ Blp = (g == 0) ? B1l : B2l;

        if (g > 0) __syncthreads();  // protect At from previous g's reads
        {
            const int r0g = row0 + grp * 8;
            int bnd[9];
            #pragma unroll
            for (int i = 0; i < 9; i++) bnd[i] = rp[min(r0g + i, nrows)];
            #pragma unroll
            for (int p = 0; p < 2; p++) {
                const int rb0 = bnd[4 * p],     rb1 = bnd[4 * p + 1];
                const int rb2 = bnd[4 * p + 2], rb3 = bnd[4 * p + 3];
                const int rb4 = bnd[4 * p + 4];
                float4 aA = make_float4(0.f, 0.f, 0.f, 0.f);
                float4 aB = make_float4(0.f, 0.f, 0.f, 0.f);
                float4 aC = make_float4(0.f, 0.f, 0.f, 0.f);
                float4 aD = make_float4(0.f, 0.f, 0.f, 0.f);
                // clamp to valid cw entries; empty rows add exact +0.0f terms
                const int lA = min(max(rb1 - 1, rb0), NE - 1);
                const int lB = min(max(rb2 - 1, rb1), NE - 1);
                const int lC = min(max(rb3 - 1, rb2), NE - 1);
                const int lD = min(max(rb4 - 1, rb3), NE - 1);
                int jA = rb0, jB = rb1, jC = rb2, jD = rb3;
                while (jA < rb1 || jB < rb2 || jC < rb3 || jD < rb4) {
                    int2 ed[16];
                    #pragma unroll
                    for (int u = 0; u < 4; u++) ed[u]      = cw[min(jA + u, lA)];
                    #pragma unroll
                    for (int u = 0; u < 4; u++) ed[4 + u]  = cw[min(jB + u, lB)];
                    #pragma unroll
                    for (int u = 0; u < 4; u++) ed[8 + u]  = cw[min(jC + u, lC)];
                    #pragma unroll
                    for (int u = 0; u < 4; u++) ed[12 + u] = cw[min(jD + u, lD)];
                    float wt[16];
                    #pragma unroll
                    for (int u = 0; u < 4; u++) {
                        wt[u]      = (jA + u < rb1) ? __int_as_float(ed[u].y)      : 0.f;
                        wt[4 + u]  = (jB + u < rb2) ? __int_as_float(ed[4 + u].y)  : 0.f;
                        wt[8 + u]  = (jC + u < rb3) ? __int_as_float(ed[8 + u].y)  : 0.f;
                        wt[12 + u] = (jD + u < rb4) ? __int_as_float(ed[12 + u].y) : 0.f;
                    }
                    float4 v[16];
                    #pragma unroll
                    for (int u = 0; u < 16; u++)
                        v[u] = *(const float4*)(xs + (size_t)ed[u].x * D + l32 * 4);
                    ACC4(aA, 0)
                    ACC4(aB, 4)
                    ACC4(aC, 8)
                    ACC4(aD, 12)
                    jA += 4; jB += 4; jC += 4; jD += 4;
                }
                const float invA = 1.0f / (float)max(rb1 - rb0, 1);
                const float invB = 1.0f / (float)max(rb2 - rb1, 1);
                const float invC = 1.0f / (float)max(rb3 - rb2, 1);
                const float invD = 1.0f / (float)max(rb4 - rb3, 1);
                aA.x *= invA; aA.y *= invA; aA.z *= invA; aA.w *= invA;
                aB.x *= invB; aB.y *= invB; aB.z *= invB; aB.w *= invB;
                aC.x *= invC; aC.y *= invC; aC.z *= invC; aC.w *= invC;
                aD.x *= invD; aD.y *= invD; aD.z *= invD; aD.w *= invD;
                const int lr0 = grp * 8 + 4 * p;
                *(float4*)&At[(lr0 + 0) * ASTR + ((l32 ^ (((lr0 + 0) & 3) << 1)) << 2)] = aA;
                *(float4*)&At[(lr0 + 1) * ASTR + ((l32 ^ (((lr0 + 1) & 3) << 1)) << 2)] = aB;
                *(float4*)&At[(lr0 + 2) * ASTR + ((l32 ^ (((lr0 + 2) & 3) << 1)) << 2)] = aC;
                *(float4*)&At[(lr0 + 3) * ASTR + ((l32 ^ (((lr0 + 3) & 3) << 1)) << 2)] = aD;
            }
        }
        __syncthreads();

        const bfrag* __restrict__ Bh = (const bfrag*)Bhp;
        const bfrag* __restrict__ Bl = (const bfrag*)Blp;
        const int rloc = w * 16 + c;
        const int sw = (rloc & 3) << 1;
        const float* __restrict__ arow_lds = &At[rloc * ASTR];
        #pragma unroll
        for (int kc = 0; kc < 4; kc++) {
            const int g0 = kc * 8 + q * 2;
            float4 a0 = *(const float4*)(arow_lds + ((g0 ^ sw) << 2));
            float4 a1 = *(const float4*)(arow_lds + (((g0 + 1) ^ sw) << 2));
            union { unsigned u[4]; bfrag v; } ahu, alu;
            split2(a0.x, a0.y, ahu.u[0], alu.u[0]);
            split2(a0.z, a0.w, ahu.u[1], alu.u[1]);
            split2(a1.x, a1.y, ahu.u[2], alu.u[2]);
            split2(a1.z, a1.w, ahu.u[3], alu.u[3]);
            bfrag ah = ahu.v, al = alu.v;
            const bfrag* bh = Bh + kc * 512 + lane;
            const bfrag* bl = Bl + kc * 512 + lane;
            #pragma unroll
            for (int nt = 0; nt < 8; nt++) {
                bfrag vh = bh[nt * 64];
                bfrag vl = bl[nt * 64];
                acc[nt] = __builtin_amdgcn_mfma_f32_16x16x32_bf16(ah, vh, acc[nt], 0, 0, 0);
                acc[nt] = __builtin_amdgcn_mfma_f32_16x16x32_bf16(ah, vl, acc[nt], 0, 0, 0);
                acc[nt] = __builtin_amdgcn_mfma_f32_16x16x32_bf16(al, vh, acc[nt], 0, 0, 0);
            }
        }
    }

    // ---- epilogue: collapse h = relu(acc+bias) through C columns in-register.
    float c00[8], c01[8], c10[8], c11[8], bvv[8];
    #pragma unroll
    for (int nt = 0; nt < 8; nt++) {
        float2 v0 = *(const float2*)(Ccol0 + (nt * 16 + c) * 2);
        c00[nt] = v0.x; c01[nt] = v0.y;
        if (NG == 2) {
            float2 v1 = *(const float2*)(Ccol1 + (nt * 16 + c) * 2);
            c10[nt] = v1.x; c11[nt] = v1.y;
        }
        bvv[nt] = bias[nt * 16 + c];
    }
    #pragma unroll
    for (int r = 0; r < 4; r++) {
        int row = row0 + w * 16 + q * 4 + r;
        float s0 = 0.f, s1 = 0.f, t0 = 0.f, t1 = 0.f;
        #pragma unroll
        for (int nt = 0; nt < 8; nt++) {
            float h = fmaxf(acc[nt][r] + bvv[nt], 0.f);
            s0 += h * c00[nt]; s1 += h * c01[nt];
            if (NG == 2) { t0 += h * c10[nt]; t1 += h * c11[nt]; }
        }
        #pragma unroll
        for (int off = 1; off < 16; off <<= 1) {
            s0 += __shfl_xor(s0, off);
            s1 += __shfl_xor(s1, off);
            if (NG == 2) { t0 += __shfl_xor(t0, off); t1 += __shfl_xor(t1, off); }
        }
        if (c == 0 && row < nrows) {
            *(float2*)(zo0 + (size_t)row * 2) = make_float2(s0, s1);
            if (NG == 2) *(float2*)(zo1 + (size_t)row * 2) = make_float2(t0, t1);
        }
    }
}

__global__ __launch_bounds__(256, 4) void fused_all_kernel(
        const float* __restrict__ xapp, const float* __restrict__ xattr,
        const short* __restrict__ PBh, const short* __restrict__ PBl,
        const int* __restrict__ rp0, const int2* __restrict__ cw0,
        const int* __restrict__ rp1, const int2* __restrict__ cw1,
        const int* __restrict__ rp2, const int2* __restrict__ cw2,
        const float* __restrict__ b1, const float* __restrict__ b1s,
        const float* __restrict__ Cs, const float* __restrict__ C2,
        const float* __restrict__ C1,
        float* __restrict__ zs, float* __restrict__ z2, float* __restrict__ za) {
    __shared__ __align__(16) float At[64 * ASTR];
    const size_t MM = (size_t)D * D;
    int b = blockIdx.x;
    if (b < GB_APP) {
        fused_body<2>(xapp, PBh + 2 * MM, PBl + 2 * MM,
                      xattr, rp1, cw1, PBh + 3 * MM, PBl + 3 * MM,
                      xapp,  rp2, cw2, PBh + 4 * MM, PBl + 4 * MM,
                      b1s, Cs, C2, zs, z2, NAPP, b * 64, At);
    } else {
        int bb = b - GB_APP;
        fused_body<1>(xattr, PBh, PBl,
                      xapp, rp0, cw0, PBh + 1 * MM, PBl + 1 * MM,
                      nullptr, nullptr, nullptr, nullptr, nullptr,
                      b1, C1, nullptr, za, nullptr, NATTR, bb * 64, At);
    }
}

// ---------------- final: out[r] = zs[r] + gath1(za)/deg1 + gath2(z2)/deg2 + bconst
__global__ __launch_bounds__(256) void final_out_kernel(
        const float* __restrict__ zs, const float* __restrict__ za,
        const float* __restrict__ z2,
        const int* __restrict__ rp1, const int2* __restrict__ cw1,
        const int* __restrict__ rp2, const int2* __restrict__ cw2,
        const float* __restrict__ bconst, float* __restrict__ out, int n) {
    int r = (blockIdx.x * 256 + threadIdx.x) >> 3;
    int l = threadIdx.x & 7;
    if (r >= n) return;
    int s0 = rp1[r], s1 = rp1[r + 1];
    float q0 = 0.f, q1 = 0.f;
    for (int j = s0 + l; j < s1; j += 8) {
        int2 e = cw1[j];
        float w = __int_as_float(e.y);
        float2 v = *(const float2*)(za + (size_t)e.x * 2);
        q0 += w * v.x; q1 += w * v.y;
    }
    float inv1 = 1.0f / (float)max(s1 - s0, 1);
    float p0 = q0 * inv1, p1 = q1 * inv1;
    s0 = rp2[r]; s1 = rp2[r + 1];
    q0 = 0.f; q1 = 0.f;
    for (int j = s0 + l; j < s1; j += 8) {
        int2 e = cw2[j];
        float w = __int_as_float(e.y);
        float2 v = *(const float2*)(z2 + (size_t)e.x * 2);
        q0 += w * v.x; q1 += w * v.y;
    }
    float inv2 = 1.0f / (float)max(s1 - s0, 1);
    p0 += q0 * inv2; p1 += q1 * inv2;
    #pragma unroll
    for (int off = 1; off < 8; off <<= 1) {
        p0 += __shfl_xor(p0, off);
        p1 += __shfl_xor(p1, off);
    }
    if (l == 0) {
        float2 s = *(const float2*)(zs + (size_t)r * 2);
        out[(size_t)r * 2 + 0] = p0 + s.x + bconst[0];
        out[(size_t)r * 2 + 1] = p1 + s.y + bconst[1];
    }
}

extern "C" void kernel_launch(void* const* d_in, const int* in_sizes, int n_in,
                              void* d_out, int out_size, void* d_ws, size_t ws_size,
                              hipStream_t stream) {
    const float* x_app   = (const float*)d_in[0];
    const float* x_attr  = (const float*)d_in[1];
    const float* ew0     = (const float*)d_in[2];
    const float* ew1     = (const float*)d_in[3];
    const float* ew2     = (const float*)d_in[4];
    const float* Wself1  = (const float*)d_in[5];
    const float* Wneigh1 = (const float*)d_in[6];
    const float* b1      = (const float*)d_in[7];
    const float* Wself2  = (const float*)d_in[8];
    const float* Wneigh2 = (const float*)d_in[9];
    const float* b2      = (const float*)d_in[10];
    const float* Wc      = (const float*)d_in[11];
    const float* bc      = (const float*)d_in[12];
    const int* src0 = (const int*)d_in[13];
    const int* dst0 = (const int*)d_in[14];
    const int* src1 = (const int*)d_in[15];
    const int* dst1 = (const int*)d_in[16];
    const int* src2 = (const int*)d_in[17];
    const int* dst2 = (const int*)d_in[18];
    float* out = (float*)d_out;

    // ---- workspace layout (4-byte units; cw blocks start at even offsets) ----
    float* ws = (float*)d_ws;
    float* h_attr = ws;                                  // NATTR*D (unused)
    float* h_app  = h_attr + (size_t)NATTR * D;          // NAPP*D (unused)
    float* b1s    = h_app  + (size_t)NAPP * D;           // D
    float* b2s    = b1s + D;                             // D
    float* za     = b2s + D;                             // NATTR*2
    float* zsv    = za + (size_t)NATTR * 2;              // NAPP*2
    float* z2v    = zsv + (size_t)NAPP * 2;              // NAPP*2
    float* Cs     = z2v + (size_t)NAPP * 2;              // 256
    float* C1     = Cs + 256;                            // 256
    float* C2     = C1 + 256;                            // 256
    float* bconst = C2 + 256;                            // 4
    int* cur  = (int*)(bconst + 4);                      // SNB*SCHUNK
    int* rp0  = cur + SNB * SCHUNK;                      // NATTR+4
    int* rp1  = rp0 + NATTR + 4;                         // NAPP+4
    int* rp2  = rp1 + NAPP + 4;                          // NAPP+4
    int* bsum = rp2 + NAPP + 4;                          // 256
    int* boff = bsum + 256;                              // 256
    int2* cw0 = (int2*)(boff + 256);                     // NE int2
    int2* cw1 = cw0 + NE;                                // NE int2
    int2* cw2 = cw1 + NE;                                // NE int2
    short* PBh = (short*)(cw2 + NE);                     // 8*D*D shorts
    short* PBl = PBh + (size_t)8 * D * D;                // 8*D*D shorts

    // ---- CSR build + weight pack: one cooperative kernel ----
    BuildArgs ba;
    ba.s0 = src0; ba.d0 = dst0; ba.e0 = ew0;
    ba.s1 = src1; ba.d1 = dst1; ba.e1 = ew1;
    ba.s2 = src2; ba.d2 = dst2; ba.e2 = ew2;
    ba.Wself1 = Wself1; ba.Wneigh1 = Wneigh1; ba.Wself2 = Wself2; ba.Wneigh2 = Wneigh2;
    ba.b1 = b1; ba.b2 = b2; ba.Wc = Wc; ba.bc = bc;
    ba.PBh = PBh; ba.PBl = PBl;
    ba.b1s = b1s; ba.b2s = b2s; ba.Cs = Cs; ba.C1 = C1; ba.C2 = C2; ba.bconst = bconst;
    ba.cur = cur; ba.rp0 = rp0; ba.rp1 = rp1; ba.rp2 = rp2; ba.bsum = bsum; ba.boff = boff;
    ba.cw0 = cw0; ba.cw1 = cw1; ba.cw2 = cw2;
    void* kargs[] = { (void*)&ba };
    hipLaunchCooperativeKernel(reinterpret_cast<void*>(build_all_kernel),
                               dim3(BUILD_GRID), dim3(256), kargs, 0, stream);

    // ---- layer 1 + collapsed layer-2 projections, one launch ----
    fused_all_kernel<<<GB_APP + GB_ATTR, 256, 0, stream>>>(
        x_app, x_attr, PBh, PBl,
        rp0, cw0, rp1, cw1, rp2, cw2,
        b1, b1s, Cs, C2, C1, zsv, z2v, za);

    // ---- final gather over collapsed 2-wide features ----
    final_out_kernel<<<((size_t)NAPP * 8 + 255) / 256, 256, 0, stream>>>(
        zsv, za, z2v, rp1, cw1, rp2, cw2, bconst, out, NAPP);
}

// Round 6
// 496.049 us; speedup vs baseline: 2.8672x; 2.8672x over previous
//
#include <hip/hip_runtime.h>

#define NAPP  100000
#define NATTR 50000
#define NE    500000
#define D     128
#define NTOT  (NATTR + 2 * NAPP)
#define SCHUNK 1024
#define SNB   ((NTOT + SCHUNK - 1) / SCHUNK)
#define EGRID ((NE + 255) / 256)
#define GB_APP  ((NAPP + 63) / 64)
#define GB_ATTR ((NATTR + 63) / 64)

typedef __attribute__((ext_vector_type(8))) short bfrag;
typedef __attribute__((ext_vector_type(4))) float f32x4;

__device__ __forceinline__ short bf16_rn(float x) {
    union { float f; unsigned u; } a; a.f = x;
    unsigned r = (a.u + 0x7fffu + ((a.u >> 16) & 1u)) >> 16;
    return (short)r;
}
__device__ __forceinline__ float bf16_to_f(short s) {
    union { float f; unsigned u; } a;
    a.u = ((unsigned)(unsigned short)s) << 16;
    return a.f;
}

// split two floats into packed bf16-hi pair and bf16-lo (residual) pair.
__device__ __forceinline__ void split2(float x, float y, unsigned& hw, unsigned& lw) {
    union { float f; unsigned u; } ax, ay;
    ax.f = x; ay.f = y;
    unsigned hx = (ax.u + 0x7fffu + ((ax.u >> 16) & 1u)) >> 16;
    unsigned hy = (ay.u + 0x7fffu + ((ay.u >> 16) & 1u)) >> 16;
    union { unsigned u; float f; } fx, fy;
    fx.u = hx << 16; fy.u = hy << 16;
    union { float f; unsigned u; } rx, ry;
    rx.f = x - fx.f; ry.f = y - fy.f;
    unsigned lx = (rx.u + 0x7fffu + ((rx.u >> 16) & 1u)) >> 16;
    unsigned ly = (ry.u + 0x7fffu + ((ry.u >> 16) & 1u)) >> 16;
    hw = (hy << 16) | (hx & 0xffffu);
    lw = (ly << 16) | (lx & 0xffffu);
}

// ---------------- merged histogram over 3 relations ----------------
__global__ __launch_bounds__(256) void hist3_kernel(
        const int* __restrict__ d0, const int* __restrict__ d1, const int* __restrict__ d2,
        int* __restrict__ h0, int* __restrict__ h1, int* __restrict__ h2) {
    int b = blockIdx.x;
    int rel = b / EGRID;
    int i = (b - rel * EGRID) * 256 + threadIdx.x;
    if (i >= NE) return;
    const int* dst = (rel == 0) ? d0 : (rel == 1) ? d1 : d2;
    int* h = (rel == 0) ? h0 : (rel == 1) ? h1 : h2;
    atomicAdd(&h[dst[i]], 1);
}

// ---------------- scan phase A ----------------
__global__ __launch_bounds__(256) void scan_partial_kernel(const int* __restrict__ cur,
                                                           int* __restrict__ bsum) {
    int b = blockIdx.x, t = threadIdx.x;
    int4 v = *((const int4*)(cur + b * SCHUNK) + t);
    int s = v.x + v.y + v.z + v.w;
    __shared__ int sd[256];
    sd[t] = s;
    __syncthreads();
    for (int off = 128; off > 0; off >>= 1) {
        if (t < off) sd[t] += sd[t + off];
        __syncthreads();
    }
    if (t == 0) bsum[b] = sd[0];
}

// ---------------- scan phase B ----------------
__global__ __launch_bounds__(256) void scan_offsets_kernel(const int* __restrict__ bsum,
        int* __restrict__ boff, int* __restrict__ rp0, int* __restrict__ rp1,
        int* __restrict__ rp2) {
    int t = threadIdx.x;
    int v = (t < SNB) ? bsum[t] : 0;
    __shared__ int sd[256];
    sd[t] = v;
    __syncthreads();
    for (int off = 1; off < 256; off <<= 1) {
        int u = (t >= off) ? sd[t - off] : 0;
        __syncthreads();
        sd[t] += u;
        __syncthreads();
    }
    boff[t] = sd[t] - v;
    if (t == 0) { rp0[NATTR] = NE; rp1[NAPP] = NE; rp2[NAPP] = NE; }
}

// ---------------- scan phase C ----------------
__global__ __launch_bounds__(256) void scan_final_kernel(int* __restrict__ cur,
        const int* __restrict__ boff, int* __restrict__ rp0, int* __restrict__ rp1,
        int* __restrict__ rp2) {
    int b = blockIdx.x, t = threadIdx.x;
    int base = b * SCHUNK + t * 4;
    int4 v = *(const int4*)(cur + base);
    int s = v.x + v.y + v.z + v.w;
    __shared__ int sd[256];
    sd[t] = s;
    __syncthreads();
    for (int off = 1; off < 256; off <<= 1) {
        int u = (t >= off) ? sd[t - off] : 0;
        __syncthreads();
        sd[t] += u;
        __syncthreads();
    }
    int pre = boff[b] + sd[t] - s;
    int ex[4];
    ex[0] = pre;
    ex[1] = ex[0] + v.x;
    ex[2] = ex[1] + v.y;
    ex[3] = ex[2] + v.z;
    #pragma unroll
    for (int i = 0; i < 4; i++) {
        int idx = base + i;
        if (idx < NTOT) {
            int* rp; int loc; int rbase;
            if (idx < NATTR)             { rp = rp0; loc = idx;                 rbase = 0; }
            else if (idx < NATTR + NAPP) { rp = rp1; loc = idx - NATTR;        rbase = NE; }
            else                         { rp = rp2; loc = idx - NATTR - NAPP; rbase = 2 * NE; }
            int val = ex[i] - rbase;
            rp[loc] = val;
            cur[idx] = val;
        }
    }
}

// ---------------- merged scatter, packed (src, ew) int2 ----------------
__global__ __launch_bounds__(256) void scatter3_kernel(
        const int* __restrict__ s0, const int* __restrict__ d0, const float* __restrict__ e0,
        int* __restrict__ c0, int2* __restrict__ cw0,
        const int* __restrict__ s1, const int* __restrict__ d1, const float* __restrict__ e1,
        int* __restrict__ c1, int2* __restrict__ cw1,
        const int* __restrict__ s2, const int* __restrict__ d2, const float* __restrict__ e2,
        int* __restrict__ c2, int2* __restrict__ cw2) {
    int b = blockIdx.x;
    int rel = b / EGRID;
    int i = (b - rel * EGRID) * 256 + threadIdx.x;
    if (i >= NE) return;
    const int* src; const int* dst; const float* ew; int* cur; int2* cw;
    if (rel == 0)      { src = s0; dst = d0; ew = e0; cur = c0; cw = cw0; }
    else if (rel == 1) { src = s1; dst = d1; ew = e1; cur = c1; cw = cw1; }
    else               { src = s2; dst = d2; ew = e2; cur = c2; cw = cw2; }
    int p = atomicAdd(&cur[dst[i]], 1);
    int2 v;
    v.x = src[i];
    v.y = __float_as_int(ew[i]);
    cw[p] = v;
}

// ---------------- pack weights + layer-2 collapsed constants ----------------
__global__ __launch_bounds__(256) void pack_kernel(
        const float* __restrict__ Wself1, const float* __restrict__ Wneigh1,
        const float* __restrict__ Wself2, const float* __restrict__ Wneigh2,
        const float* __restrict__ b1, const float* __restrict__ b2,
        const float* __restrict__ Wc, const float* __restrict__ bc,
        short* __restrict__ PBh, short* __restrict__ PBl,
        float* __restrict__ b1s, float* __restrict__ b2s,
        float* __restrict__ Cs, float* __restrict__ C1, float* __restrict__ C2,
        float* __restrict__ bconst) {
    int m = blockIdx.x;
    if (m == 8) {
        int tid = threadIdx.x;
        int k = tid >> 1, j = tid & 1;
        const float* Wn1 = Wneigh2 + D * D;
        const float* Wn2 = Wneigh2 + 2 * D * D;
        const float* Ws1 = Wself2 + D * D;
        const float* Ws2 = Wself2 + 2 * D * D;
        float ss = 0.f, s1 = 0.f, s2 = 0.f;
        for (int tt = 0; tt < D; tt++) {
            float wc = Wc[tt * 2 + j];
            ss += (Ws1[k * D + tt] + Ws2[k * D + tt]) * wc;
            s1 += Wn1[k * D + tt] * wc;
            s2 += Wn2[k * D + tt] * wc;
        }
        Cs[tid] = ss; C1[tid] = s1; C2[tid] = s2;
        if (tid < 2) {
            float s = bc[tid];
            for (int tt = 0; tt < D; tt++)
                s += (b2[D + tt] + b2[2 * D + tt]) * Wc[tt * 2 + tid];
            bconst[tid] = s;
        }
        return;
    }
    const float* srcA; const float* srcB = nullptr;
    switch (m) {
        case 0: srcA = Wself1; break;
        case 1: srcA = Wneigh1; break;
        case 2: srcA = Wself1 + D * D; srcB = Wself1 + 2 * D * D; break;
        case 3: srcA = Wneigh1 + D * D; break;
        case 4: srcA = Wneigh1 + 2 * D * D; break;
        case 5: srcA = Wself2 + D * D; srcB = Wself2 + 2 * D * D; break;
        case 6: srcA = Wneigh2 + D * D; break;
        default: srcA = Wneigh2 + 2 * D * D; break;
    }
    short* oh = PBh + (size_t)m * D * D;
    short* ol = PBl + (size_t)m * D * D;
    for (int i = threadIdx.x; i < D * D; i += 256) {
        int k = i >> 7, n = i & 127;
        float v = srcA[i];
        if (srcB) v += srcB[i];
        short hi = bf16_rn(v);
        short lo = bf16_rn(v - bf16_to_f(hi));
        int kc = k >> 5, q = (k >> 3) & 3, j = k & 7, nt = n >> 4, c = n & 15;
        int pos = (((kc * 8 + nt) * 64) + q * 16 + c) * 8 + j;
        oh[pos] = hi;
        ol[pos] = lo;
    }
    if (m == 0 && threadIdx.x < D) {
        int t = threadIdx.x;
        b1s[t] = b1[D + t] + b1[2 * D + t];
        b2s[t] = b2[D + t] + b2[2 * D + t];
    }
}

// ---------------- fused gather + MFMA node update + collapsed classifier ----
// Pair-interleaved gather (round-4 structure) + next-iteration cw prefetch:
// cw loads for iteration i+1 issue before iteration i's x-row waitcnt, hiding
// cw latency under x latency. Tested under (256,4) cap (128 VGPR): base use is
// 64, prefetch adds ~16 live regs -> no spill expected (verify via VGPR_Count
// and WRITE_SIZE). FMA order bitwise-identical; clamped prefetch is in-bounds.
#define ASTR 128
template<int NG>
__device__ __forceinline__ void fused_body(
        const float* __restrict__ in0, const short* __restrict__ B0h, const short* __restrict__ B0l,
        const float* __restrict__ x1, const int* __restrict__ rp1, const int2* __restrict__ cw1,
        const short* __restrict__ B1h, const short* __restrict__ B1l,
        const float* __restrict__ x2, const int* __restrict__ rp2, const int2* __restrict__ cw2,
        const short* __restrict__ B2h, const short* __restrict__ B2l,
        const float* __restrict__ bias,
        const float* __restrict__ Ccol0, const float* __restrict__ Ccol1,
        float* __restrict__ zo0, float* __restrict__ zo1,
        int nrows, int row0, float* At) {
    const int t = threadIdx.x;
    const int w = t >> 6, lane = t & 63;
    const int q = lane >> 4, c = lane & 15;
    const int myrow = row0 + w * 16 + c;
    const int arow = min(myrow, nrows - 1);

    f32x4 acc[8];
    #pragma unroll
    for (int nt = 0; nt < 8; nt++) acc[nt] = (f32x4){0.f, 0.f, 0.f, 0.f};

    // ---- direct (self) source: global -> reg fragments ----
    {
        const float* __restrict__ arp = in0 + (size_t)arow * D;
        const bfrag* __restrict__ Bh = (const bfrag*)B0h;
        const bfrag* __restrict__ Bl = (const bfrag*)B0l;
        #pragma unroll
        for (int kc = 0; kc < 4; kc++) {
            float4 a0 = *(const float4*)(arp + kc * 32 + q * 8);
            float4 a1 = *(const float4*)(arp + kc * 32 + q * 8 + 4);
            union { unsigned u[4]; bfrag v; } ahu, alu;
            split2(a0.x, a0.y, ahu.u[0], alu.u[0]);
            split2(a0.z, a0.w, ahu.u[1], alu.u[1]);
            split2(a1.x, a1.y, ahu.u[2], alu.u[2]);
            split2(a1.z, a1.w, ahu.u[3], alu.u[3]);
            bfrag ah = ahu.v, al = alu.v;
            const bfrag* bh = Bh + kc * 512 + lane;
            const bfrag* bl = Bl + kc * 512 + lane;
            #pragma unroll
            for (int nt = 0; nt < 8; nt++) {
                bfrag vh = bh[nt * 64];
                bfrag vl = bl[nt * 64];
                acc[nt] = __builtin_amdgcn_mfma_f32_16x16x32_bf16(ah, vh, acc[nt], 0, 0, 0);
                acc[nt] = __builtin_amdgcn_mfma_f32_16x16x32_bf16(ah, vl, acc[nt], 0, 0, 0);
                acc[nt] = __builtin_amdgcn_mfma_f32_16x16x32_bf16(al, vh, acc[nt], 0, 0, 0);
            }
        }
    }

    // ---- gathered sources: cooperative gather -> LDS -> MFMA ----
    const int grp = t >> 5, l32 = t & 31;
    #pragma unroll
    for (int g = 0; g < NG; g++) {
        const float* __restrict__ xs = (g == 0) ? x1 : x2;
        const int* __restrict__ rp   = (g == 0) ? rp1 : rp2;
        const int2* __restrict__ cw  = (g == 0) ? cw1 : cw2;
        const short* __restrict__ Bhp = (g == 0) ? B1h : B2h;
        const short* __restrict__ Blp = (g == 0) ? B1l : B2l;

        if (g > 0) __syncthreads();  // protect At from previous g's reads
        {
            const int r0g = row0 + grp * 8;
            int bnd[9];
            #pragma unroll
            for (int i = 0; i < 9; i++) bnd[i] = rp[min(r0g + i, nrows)];
            #pragma unroll
            for (int p = 0; p < 4; p++) {
                const int A0 = bnd[2 * p],     A1 = bnd[2 * p + 1];
                const int B0 = bnd[2 * p + 1], B1 = bnd[2 * p + 2];
                float4 aA = make_float4(0.f, 0.f, 0.f, 0.f);
                float4 aB = make_float4(0.f, 0.f, 0.f, 0.f);
                // clamp to valid cw entries; empty rows add exact +0.0f terms
                const int lastA = min(max(A1 - 1, A0), NE - 1);
                const int lastB = min(max(B1 - 1, B0), NE - 1);
                int jA = A0, jB = B0;
                int2 ed[8];
                #pragma unroll
                for (int u = 0; u < 4; u++) ed[u] = cw[min(jA + u, lastA)];
                #pragma unroll
                for (int u = 0; u < 4; u++) ed[4 + u] = cw[min(jB + u, lastB)];
                while (jA < A1 || jB < B1) {
                    float wt[8];
                    int idx[8];
                    #pragma unroll
                    for (int u = 0; u < 4; u++) {
                        wt[u] = (jA + u < A1) ? __int_as_float(ed[u].y) : 0.f;
                        idx[u] = ed[u].x;
                    }
                    #pragma unroll
                    for (int u = 0; u < 4; u++) {
                        wt[4 + u] = (jB + u < B1) ? __int_as_float(ed[4 + u].y) : 0.f;
                        idx[4 + u] = ed[4 + u].x;
                    }
                    jA += 4; jB += 4;
                    // prefetch next-iteration cw (clamped, branch-free, in-bounds);
                    // issues before the x-row waitcnt so its latency is hidden.
                    #pragma unroll
                    for (int u = 0; u < 4; u++) ed[u] = cw[min(jA + u, lastA)];
                    #pragma unroll
                    for (int u = 0; u < 4; u++) ed[4 + u] = cw[min(jB + u, lastB)];
                    float4 v[8];
                    #pragma unroll
                    for (int u = 0; u < 8; u++)
                        v[u] = *(const float4*)(xs + (size_t)idx[u] * D + l32 * 4);
                    aA.x += wt[0] * v[0].x + wt[1] * v[1].x + wt[2] * v[2].x + wt[3] * v[3].x;
                    aA.y += wt[0] * v[0].y + wt[1] * v[1].y + wt[2] * v[2].y + wt[3] * v[3].y;
                    aA.z += wt[0] * v[0].z + wt[1] * v[1].z + wt[2] * v[2].z + wt[3] * v[3].z;
                    aA.w += wt[0] * v[0].w + wt[1] * v[1].w + wt[2] * v[2].w + wt[3] * v[3].w;
                    aB.x += wt[4] * v[4].x + wt[5] * v[5].x + wt[6] * v[6].x + wt[7] * v[7].x;
                    aB.y += wt[4] * v[4].y + wt[5] * v[5].y + wt[6] * v[6].y + wt[7] * v[7].y;
                    aB.z += wt[4] * v[4].z + wt[5] * v[5].z + wt[6] * v[6].z + wt[7] * v[7].z;
                    aB.w += wt[4] * v[4].w + wt[5] * v[5].w + wt[6] * v[6].w + wt[7] * v[7].w;
                }
                const float invA = 1.0f / (float)max(A1 - A0, 1);
                const float invB = 1.0f / (float)max(B1 - B0, 1);
                aA.x *= invA; aA.y *= invA; aA.z *= invA; aA.w *= invA;
                aB.x *= invB; aB.y *= invB; aB.z *= invB; aB.w *= invB;
                const int lrA = grp * 8 + 2 * p;
                const int lrB = lrA + 1;
                *(float4*)&At[lrA * ASTR + ((l32 ^ ((lrA & 3) << 1)) << 2)] = aA;
                *(float4*)&At[lrB * ASTR + ((l32 ^ ((lrB & 3) << 1)) << 2)] = aB;
            }
        }
        __syncthreads();

        const bfrag* __restrict__ Bh = (const bfrag*)Bhp;
        const bfrag* __restrict__ Bl = (const bfrag*)Blp;
        const int rloc = w * 16 + c;
        const int sw = (rloc & 3) << 1;
        const float* __restrict__ arow_lds = &At[rloc * ASTR];
        #pragma unroll
        for (int kc = 0; kc < 4; kc++) {
            const int g0 = kc * 8 + q * 2;
            float4 a0 = *(const float4*)(arow_lds + ((g0 ^ sw) << 2));
            float4 a1 = *(const float4*)(arow_lds + (((g0 + 1) ^ sw) << 2));
            union { unsigned u[4]; bfrag v; } ahu, alu;
            split2(a0.x, a0.y, ahu.u[0], alu.u[0]);
            split2(a0.z, a0.w, ahu.u[1], alu.u[1]);
            split2(a1.x, a1.y, ahu.u[2], alu.u[2]);
            split2(a1.z, a1.w, ahu.u[3], alu.u[3]);
            bfrag ah = ahu.v, al = alu.v;
            const bfrag* bh = Bh + kc * 512 + lane;
            const bfrag* bl = Bl + kc * 512 + lane;
            #pragma unroll
            for (int nt = 0; nt < 8; nt++) {
                bfrag vh = bh[nt * 64];
                bfrag vl = bl[nt * 64];
                acc[nt] = __builtin_amdgcn_mfma_f32_16x16x32_bf16(ah, vh, acc[nt], 0, 0, 0);
                acc[nt] = __builtin_amdgcn_mfma_f32_16x16x32_bf16(ah, vl, acc[nt], 0, 0, 0);
                acc[nt] = __builtin_amdgcn_mfma_f32_16x16x32_bf16(al, vh, acc[nt], 0, 0, 0);
            }
        }
    }

    // ---- epilogue: collapse h = relu(acc+bias) through C columns in-register.
    float c00[8], c01[8], c10[8], c11[8], bvv[8];
    #pragma unroll
    for (int nt = 0; nt < 8; nt++) {
        float2 v0 = *(const float2*)(Ccol0 + (nt * 16 + c) * 2);
        c00[nt] = v0.x; c01[nt] = v0.y;
        if (NG == 2) {
            float2 v1 = *(const float2*)(Ccol1 + (nt * 16 + c) * 2);
            c10[nt] = v1.x; c11[nt] = v1.y;
        }
        bvv[nt] = bias[nt * 16 + c];
    }
    #pragma unroll
    for (int r = 0; r < 4; r++) {
        int row = row0 + w * 16 + q * 4 + r;
        float s0 = 0.f, s1 = 0.f, t0 = 0.f, t1 = 0.f;
        #pragma unroll
        for (int nt = 0; nt < 8; nt++) {
            float h = fmaxf(acc[nt][r] + bvv[nt], 0.f);
            s0 += h * c00[nt]; s1 += h * c01[nt];
            if (NG == 2) { t0 += h * c10[nt]; t1 += h * c11[nt]; }
        }
        #pragma unroll
        for (int off = 1; off < 16; off <<= 1) {
            s0 += __shfl_xor(s0, off);
            s1 += __shfl_xor(s1, off);
            if (NG == 2) { t0 += __shfl_xor(t0, off); t1 += __shfl_xor(t1, off); }
        }
        if (c == 0 && row < nrows) {
            *(float2*)(zo0 + (size_t)row * 2) = make_float2(s0, s1);
            if (NG == 2) *(float2*)(zo1 + (size_t)row * 2) = make_float2(t0, t1);
        }
    }
}

__global__ __launch_bounds__(256, 4) void fused_all_kernel(
        const float* __restrict__ xapp, const float* __restrict__ xattr,
        const short* __restrict__ PBh, const short* __restrict__ PBl,
        const int* __restrict__ rp0, const int2* __restrict__ cw0,
        const int* __restrict__ rp1, const int2* __restrict__ cw1,
        const int* __restrict__ rp2, const int2* __restrict__ cw2,
        const float* __restrict__ b1, const float* __restrict__ b1s,
        const float* __restrict__ Cs, const float* __restrict__ C2,
        const float* __restrict__ C1,
        float* __restrict__ zs, float* __restrict__ z2, float* __restrict__ za) {
    __shared__ __align__(16) float At[64 * ASTR];
    const size_t MM = (size_t)D * D;
    int b = blockIdx.x;
    if (b < GB_APP) {
        fused_body<2>(xapp, PBh + 2 * MM, PBl + 2 * MM,
                      xattr, rp1, cw1, PBh + 3 * MM, PBl + 3 * MM,
                      xapp,  rp2, cw2, PBh + 4 * MM, PBl + 4 * MM,
                      b1s, Cs, C2, zs, z2, NAPP, b * 64, At);
    } else {
        int bb = b - GB_APP;
        fused_body<1>(xattr, PBh, PBl,
                      xapp, rp0, cw0, PBh + 1 * MM, PBl + 1 * MM,
                      nullptr, nullptr, nullptr, nullptr, nullptr,
                      b1, C1, nullptr, za, nullptr, NATTR, bb * 64, At);
    }
}

// ---------------- final: out[r] = zs[r] + gath1(za)/deg1 + gath2(z2)/deg2 + bconst
__global__ __launch_bounds__(256) void final_out_kernel(
        const float* __restrict__ zs, const float* __restrict__ za,
        const float* __restrict__ z2,
        const int* __restrict__ rp1, const int2* __restrict__ cw1,
        const int* __restrict__ rp2, const int2* __restrict__ cw2,
        const float* __restrict__ bconst, float* __restrict__ out, int n) {
    int r = (blockIdx.x * 256 + threadIdx.x) >> 3;
    int l = threadIdx.x & 7;
    if (r >= n) return;
    int s0 = rp1[r], s1 = rp1[r + 1];
    float q0 = 0.f, q1 = 0.f;
    for (int j = s0 + l; j < s1; j += 8) {
        int2 e = cw1[j];
        float w = __int_as_float(e.y);
        float2 v = *(const float2*)(za + (size_t)e.x * 2);
        q0 += w * v.x; q1 += w * v.y;
    }
    float inv1 = 1.0f / (float)max(s1 - s0, 1);
    float p0 = q0 * inv1, p1 = q1 * inv1;
    s0 = rp2[r]; s1 = rp2[r + 1];
    q0 = 0.f; q1 = 0.f;
    for (int j = s0 + l; j < s1; j += 8) {
        int2 e = cw2[j];
        float w = __int_as_float(e.y);
        float2 v = *(const float2*)(z2 + (size_t)e.x * 2);
        q0 += w * v.x; q1 += w * v.y;
    }
    float inv2 = 1.0f / (float)max(s1 - s0, 1);
    p0 += q0 * inv2; p1 += q1 * inv2;
    #pragma unroll
    for (int off = 1; off < 8; off <<= 1) {
        p0 += __shfl_xor(p0, off);
        p1 += __shfl_xor(p1, off);
    }
    if (l == 0) {
        float2 s = *(const float2*)(zs + (size_t)r * 2);
        out[(size_t)r * 2 + 0] = p0 + s.x + bconst[0];
        out[(size_t)r * 2 + 1] = p1 + s.y + bconst[1];
    }
}

extern "C" void kernel_launch(void* const* d_in, const int* in_sizes, int n_in,
                              void* d_out, int out_size, void* d_ws, size_t ws_size,
                              hipStream_t stream) {
    const float* x_app   = (const float*)d_in[0];
    const float* x_attr  = (const float*)d_in[1];
    const float* ew0     = (const float*)d_in[2];
    const float* ew1     = (const float*)d_in[3];
    const float* ew2     = (const float*)d_in[4];
    const float* Wself1  = (const float*)d_in[5];
    const float* Wneigh1 = (const float*)d_in[6];
    const float* b1      = (const float*)d_in[7];
    const float* Wself2  = (const float*)d_in[8];
    const float* Wneigh2 = (const float*)d_in[9];
    const float* b2      = (const float*)d_in[10];
    const float* Wc      = (const float*)d_in[11];
    const float* bc      = (const float*)d_in[12];
    const int* src0 = (const int*)d_in[13];
    const int* dst0 = (const int*)d_in[14];
    const int* src1 = (const int*)d_in[15];
    const int* dst1 = (const int*)d_in[16];
    const int* src2 = (const int*)d_in[17];
    const int* dst2 = (const int*)d_in[18];
    float* out = (float*)d_out;

    // ---- workspace layout (4-byte units; cw blocks start at even offsets) ----
    float* ws = (float*)d_ws;
    float* h_attr = ws;                                  // NATTR*D (unused)
    float* h_app  = h_attr + (size_t)NATTR * D;          // NAPP*D (unused)
    float* b1s    = h_app  + (size_t)NAPP * D;           // D
    float* b2s    = b1s + D;                             // D
    float* za     = b2s + D;                             // NATTR*2
    float* zsv    = za + (size_t)NATTR * 2;              // NAPP*2
    float* z2v    = zsv + (size_t)NAPP * 2;              // NAPP*2
    float* Cs     = z2v + (size_t)NAPP * 2;              // 256
    float* C1     = Cs + 256;                            // 256
    float* C2     = C1 + 256;                            // 256
    float* bconst = C2 + 256;                            // 4
    int* cur  = (int*)(bconst + 4);                      // SNB*SCHUNK
    int* cur0 = cur;
    int* cur1 = cur0 + NATTR;
    int* cur2 = cur1 + NAPP;
    int* rp0  = cur + SNB * SCHUNK;                      // NATTR+4
    int* rp1  = rp0 + NATTR + 4;                         // NAPP+4
    int* rp2  = rp1 + NAPP + 4;                          // NAPP+4
    int* bsum = rp2 + NAPP + 4;                          // 256
    int* boff = bsum + 256;                              // 256
    int2* cw0 = (int2*)(boff + 256);                     // NE int2
    int2* cw1 = cw0 + NE;                                // NE int2
    int2* cw2 = cw1 + NE;                                // NE int2
    short* PBh = (short*)(cw2 + NE);                     // 8*D*D shorts
    short* PBl = PBh + (size_t)8 * D * D;                // 8*D*D shorts

    hipMemsetAsync(cur, 0, (size_t)SNB * SCHUNK * sizeof(int), stream);

    pack_kernel<<<9, 256, 0, stream>>>(Wself1, Wneigh1, Wself2, Wneigh2,
                                       b1, b2, Wc, bc, PBh, PBl, b1s, b2s,
                                       Cs, C1, C2, bconst);

    // ---- CSR build ----
    hist3_kernel<<<3 * EGRID, 256, 0, stream>>>(dst0, dst1, dst2, cur0, cur1, cur2);
    scan_partial_kernel<<<SNB, 256, 0, stream>>>(cur, bsum);
    scan_offsets_kernel<<<1, 256, 0, stream>>>(bsum, boff, rp0, rp1, rp2);
    scan_final_kernel<<<SNB, 256, 0, stream>>>(cur, boff, rp0, rp1, rp2);
    scatter3_kernel<<<3 * EGRID, 256, 0, stream>>>(
        src0, dst0, ew0, cur0, cw0,
        src1, dst1, ew1, cur1, cw1,
        src2, dst2, ew2, cur2, cw2);

    // ---- layer 1 + collapsed layer-2 projections, one launch ----
    fused_all_kernel<<<GB_APP + GB_ATTR, 256, 0, stream>>>(
        x_app, x_attr, PBh, PBl,
        rp0, cw0, rp1, cw1, rp2, cw2,
        b1, b1s, Cs, C2, C1, zsv, z2v, za);

    // ---- final gather over collapsed 2-wide features ----
    final_out_kernel<<<((size_t)NAPP * 8 + 255) / 256, 256, 0, stream>>>(
        zsv, za, z2v, rp1, cw1, rp2, cw2, bconst, out, NAPP);
}

// Round 8
// 490.413 us; speedup vs baseline: 2.9001x; 1.0115x over previous
//
#include <hip/hip_runtime.h>

#define NAPP  100000
#define NATTR 50000
#define NE    500000
#define D     128
#define NTOT  (NATTR + 2 * NAPP)
#define SCHUNK 1024
#define SNB   ((NTOT + SCHUNK - 1) / SCHUNK)
#define EGRID ((NE + 255) / 256)
#define GB_APP  ((NAPP + 63) / 64)
#define GB_ATTR ((NATTR + 63) / 64)
#define ECAP  1024

typedef __attribute__((ext_vector_type(8))) short bfrag;
typedef __attribute__((ext_vector_type(4))) float f32x4;

__device__ __forceinline__ short bf16_rn(float x) {
    union { float f; unsigned u; } a; a.f = x;
    unsigned r = (a.u + 0x7fffu + ((a.u >> 16) & 1u)) >> 16;
    return (short)r;
}
__device__ __forceinline__ float bf16_to_f(short s) {
    union { float f; unsigned u; } a;
    a.u = ((unsigned)(unsigned short)s) << 16;
    return a.f;
}

// split two floats into packed bf16-hi pair and bf16-lo (residual) pair.
__device__ __forceinline__ void split2(float x, float y, unsigned& hw, unsigned& lw) {
    union { float f; unsigned u; } ax, ay;
    ax.f = x; ay.f = y;
    unsigned hx = (ax.u + 0x7fffu + ((ax.u >> 16) & 1u)) >> 16;
    unsigned hy = (ay.u + 0x7fffu + ((ay.u >> 16) & 1u)) >> 16;
    union { unsigned u; float f; } fx, fy;
    fx.u = hx << 16; fy.u = hy << 16;
    union { float f; unsigned u; } rx, ry;
    rx.f = x - fx.f; ry.f = y - fy.f;
    unsigned lx = (rx.u + 0x7fffu + ((rx.u >> 16) & 1u)) >> 16;
    unsigned ly = (ry.u + 0x7fffu + ((ry.u >> 16) & 1u)) >> 16;
    hw = (hy << 16) | (hx & 0xffffu);
    lw = (ly << 16) | (lx & 0xffffu);
}

// ---------------- merged histogram over 3 relations ----------------
__global__ __launch_bounds__(256) void hist3_kernel(
        const int* __restrict__ d0, const int* __restrict__ d1, const int* __restrict__ d2,
        int* __restrict__ h0, int* __restrict__ h1, int* __restrict__ h2) {
    int b = blockIdx.x;
    int rel = b / EGRID;
    int i = (b - rel * EGRID) * 256 + threadIdx.x;
    if (i >= NE) return;
    const int* dst = (rel == 0) ? d0 : (rel == 1) ? d1 : d2;
    int* h = (rel == 0) ? h0 : (rel == 1) ? h1 : h2;
    atomicAdd(&h[dst[i]], 1);
}

// ---------------- scan phase A ----------------
__global__ __launch_bounds__(256) void scan_partial_kernel(const int* __restrict__ cur,
                                                           int* __restrict__ bsum) {
    int b = blockIdx.x, t = threadIdx.x;
    int4 v = *((const int4*)(cur + b * SCHUNK) + t);
    int s = v.x + v.y + v.z + v.w;
    __shared__ int sd[256];
    sd[t] = s;
    __syncthreads();
    for (int off = 128; off > 0; off >>= 1) {
        if (t < off) sd[t] += sd[t + off];
        __syncthreads();
    }
    if (t == 0) bsum[b] = sd[0];
}

// ---------------- scan phase B ----------------
__global__ __launch_bounds__(256) void scan_offsets_kernel(const int* __restrict__ bsum,
        int* __restrict__ boff, int* __restrict__ rp0, int* __restrict__ rp1,
        int* __restrict__ rp2) {
    int t = threadIdx.x;
    int v = (t < SNB) ? bsum[t] : 0;
    __shared__ int sd[256];
    sd[t] = v;
    __syncthreads();
    for (int off = 1; off < 256; off <<= 1) {
        int u = (t >= off) ? sd[t - off] : 0;
        __syncthreads();
        sd[t] += u;
        __syncthreads();
    }
    boff[t] = sd[t] - v;
    if (t == 0) { rp0[NATTR] = NE; rp1[NAPP] = NE; rp2[NAPP] = NE; }
}

// ---------------- scan phase C ----------------
__global__ __launch_bounds__(256) void scan_final_kernel(int* __restrict__ cur,
        const int* __restrict__ boff, int* __restrict__ rp0, int* __restrict__ rp1,
        int* __restrict__ rp2) {
    int b = blockIdx.x, t = threadIdx.x;
    int base = b * SCHUNK + t * 4;
    int4 v = *(const int4*)(cur + base);
    int s = v.x + v.y + v.z + v.w;
    __shared__ int sd[256];
    sd[t] = s;
    __syncthreads();
    for (int off = 1; off < 256; off <<= 1) {
        int u = (t >= off) ? sd[t - off] : 0;
        __syncthreads();
        sd[t] += u;
        __syncthreads();
    }
    int pre = boff[b] + sd[t] - s;
    int ex[4];
    ex[0] = pre;
    ex[1] = ex[0] + v.x;
    ex[2] = ex[1] + v.y;
    ex[3] = ex[2] + v.z;
    #pragma unroll
    for (int i = 0; i < 4; i++) {
        int idx = base + i;
        if (idx < NTOT) {
            int* rp; int loc; int rbase;
            if (idx < NATTR)             { rp = rp0; loc = idx;                 rbase = 0; }
            else if (idx < NATTR + NAPP) { rp = rp1; loc = idx - NATTR;        rbase = NE; }
            else                         { rp = rp2; loc = idx - NATTR - NAPP; rbase = 2 * NE; }
            int val = ex[i] - rbase;
            rp[loc] = val;
            cur[idx] = val;
        }
    }
}

// ---------------- merged scatter, packed (src, ew) int2 ----------------
__global__ __launch_bounds__(256) void scatter3_kernel(
        const int* __restrict__ s0, const int* __restrict__ d0, const float* __restrict__ e0,
        int* __restrict__ c0, int2* __restrict__ cw0,
        const int* __restrict__ s1, const int* __restrict__ d1, const float* __restrict__ e1,
        int* __restrict__ c1, int2* __restrict__ cw1,
        const int* __restrict__ s2, const int* __restrict__ d2, const float* __restrict__ e2,
        int* __restrict__ c2, int2* __restrict__ cw2) {
    int b = blockIdx.x;
    int rel = b / EGRID;
    int i = (b - rel * EGRID) * 256 + threadIdx.x;
    if (i >= NE) return;
    const int* src; const int* dst; const float* ew; int* cur; int2* cw;
    if (rel == 0)      { src = s0; dst = d0; ew = e0; cur = c0; cw = cw0; }
    else if (rel == 1) { src = s1; dst = d1; ew = e1; cur = c1; cw = cw1; }
    else               { src = s2; dst = d2; ew = e2; cur = c2; cw = cw2; }
    int p = atomicAdd(&cur[dst[i]], 1);
    int2 v;
    v.x = src[i];
    v.y = __float_as_int(ew[i]);
    cw[p] = v;
}

// ---------------- pack weights + layer-2 collapsed constants ----------------
__global__ __launch_bounds__(256) void pack_kernel(
        const float* __restrict__ Wself1, const float* __restrict__ Wneigh1,
        const float* __restrict__ Wself2, const float* __restrict__ Wneigh2,
        const float* __restrict__ b1, const float* __restrict__ b2,
        const float* __restrict__ Wc, const float* __restrict__ bc,
        short* __restrict__ PBh, short* __restrict__ PBl,
        float* __restrict__ b1s, float* __restrict__ b2s,
        float* __restrict__ Cs, float* __restrict__ C1, float* __restrict__ C2,
        float* __restrict__ bconst) {
    int m = blockIdx.x;
    if (m == 8) {
        int tid = threadIdx.x;
        int k = tid >> 1, j = tid & 1;
        const float* Wn1 = Wneigh2 + D * D;
        const float* Wn2 = Wneigh2 + 2 * D * D;
        const float* Ws1 = Wself2 + D * D;
        const float* Ws2 = Wself2 + 2 * D * D;
        float ss = 0.f, s1 = 0.f, s2 = 0.f;
        for (int tt = 0; tt < D; tt++) {
            float wc = Wc[tt * 2 + j];
            ss += (Ws1[k * D + tt] + Ws2[k * D + tt]) * wc;
            s1 += Wn1[k * D + tt] * wc;
            s2 += Wn2[k * D + tt] * wc;
        }
        Cs[tid] = ss; C1[tid] = s1; C2[tid] = s2;
        if (tid < 2) {
            float s = bc[tid];
            for (int tt = 0; tt < D; tt++)
                s += (b2[D + tt] + b2[2 * D + tt]) * Wc[tt * 2 + tid];
            bconst[tid] = s;
        }
        return;
    }
    const float* srcA; const float* srcB = nullptr;
    switch (m) {
        case 0: srcA = Wself1; break;
        case 1: srcA = Wneigh1; break;
        case 2: srcA = Wself1 + D * D; srcB = Wself1 + 2 * D * D; break;
        case 3: srcA = Wneigh1 + D * D; break;
        case 4: srcA = Wneigh1 + 2 * D * D; break;
        case 5: srcA = Wself2 + D * D; srcB = Wself2 + 2 * D * D; break;
        case 6: srcA = Wneigh2 + D * D; break;
        default: srcA = Wneigh2 + 2 * D * D; break;
    }
    short* oh = PBh + (size_t)m * D * D;
    short* ol = PBl + (size_t)m * D * D;
    for (int i = threadIdx.x; i < D * D; i += 256) {
        int k = i >> 7, n = i & 127;
        float v = srcA[i];
        if (srcB) v += srcB[i];
        short hi = bf16_rn(v);
        short lo = bf16_rn(v - bf16_to_f(hi));
        int kc = k >> 5, q = (k >> 3) & 3, j = k & 7, nt = n >> 4, c = n & 15;
        int pos = (((kc * 8 + nt) * 64) + q * 16 + c) * 8 + j;
        oh[pos] = hi;
        ol[pos] = lo;
    }
    if (m == 0 && threadIdx.x < D) {
        int t = threadIdx.x;
        b1s[t] = b1[D + t] + b1[2 * D + t];
        b2s[t] = b2[D + t] + b2[2 * D + t];
    }
}

// ---------------- fused gather + MFMA node update + collapsed classifier ----
// LDS edge staging (round-7 idea, OOB fix): the block's edge window
// cw[rp[row0]..rp[row0+64]) is cooperatively staged into LDS; per-row loops
// read descriptors from LDS (~120cy) instead of global (~300-900cy), with zero
// added VGPR pressure. FIX vs round 7: staged reads are clamped to [0, ecnt]
// and eds[ecnt] is a dummy {0,0} entry (staged requires ecnt < ECAP), so every
// clamped (weight-0) read hits initialized LDS and a valid x row -> no OOB.
// Same clamping semantics & FMA order -> bitwise-identical results.
#define ASTR 128
template<int NG>
__device__ __forceinline__ void fused_body(
        const float* __restrict__ in0, const short* __restrict__ B0h, const short* __restrict__ B0l,
        const float* __restrict__ x1, const int* __restrict__ rp1, const int2* __restrict__ cw1,
        const short* __restrict__ B1h, const short* __restrict__ B1l,
        const float* __restrict__ x2, const int* __restrict__ rp2, const int2* __restrict__ cw2,
        const short* __restrict__ B2h, const short* __restrict__ B2l,
        const float* __restrict__ bias,
        const float* __restrict__ Ccol0, const float* __restrict__ Ccol1,
        float* __restrict__ zo0, float* __restrict__ zo1,
        int nrows, int row0, float* At, int2* eds) {
    const int t = threadIdx.x;
    const int w = t >> 6, lane = t & 63;
    const int q = lane >> 4, c = lane & 15;
    const int myrow = row0 + w * 16 + c;
    const int arow = min(myrow, nrows - 1);

    f32x4 acc[8];
    #pragma unroll
    for (int nt = 0; nt < 8; nt++) acc[nt] = (f32x4){0.f, 0.f, 0.f, 0.f};

    // ---- direct (self) source: global -> reg fragments ----
    {
        const float* __restrict__ arp = in0 + (size_t)arow * D;
        const bfrag* __restrict__ Bh = (const bfrag*)B0h;
        const bfrag* __restrict__ Bl = (const bfrag*)B0l;
        #pragma unroll
        for (int kc = 0; kc < 4; kc++) {
            float4 a0 = *(const float4*)(arp + kc * 32 + q * 8);
            float4 a1 = *(const float4*)(arp + kc * 32 + q * 8 + 4);
            union { unsigned u[4]; bfrag v; } ahu, alu;
            split2(a0.x, a0.y, ahu.u[0], alu.u[0]);
            split2(a0.z, a0.w, ahu.u[1], alu.u[1]);
            split2(a1.x, a1.y, ahu.u[2], alu.u[2]);
            split2(a1.z, a1.w, ahu.u[3], alu.u[3]);
            bfrag ah = ahu.v, al = alu.v;
            const bfrag* bh = Bh + kc * 512 + lane;
            const bfrag* bl = Bl + kc * 512 + lane;
            #pragma unroll
            for (int nt = 0; nt < 8; nt++) {
                bfrag vh = bh[nt * 64];
                bfrag vl = bl[nt * 64];
                acc[nt] = __builtin_amdgcn_mfma_f32_16x16x32_bf16(ah, vh, acc[nt], 0, 0, 0);
                acc[nt] = __builtin_amdgcn_mfma_f32_16x16x32_bf16(ah, vl, acc[nt], 0, 0, 0);
                acc[nt] = __builtin_amdgcn_mfma_f32_16x16x32_bf16(al, vh, acc[nt], 0, 0, 0);
            }
        }
    }

    // ---- gathered sources: stage edges -> LDS, gather -> LDS, MFMA ----
    const int grp = t >> 5, l32 = t & 31;
    #pragma unroll
    for (int g = 0; g < NG; g++) {
        const float* __restrict__ xs = (g == 0) ? x1 : x2;
        const int* __restrict__ rp   = (g == 0) ? rp1 : rp2;
        const int2* __restrict__ cw  = (g == 0) ? cw1 : cw2;
        const short* __restrict__ Bhp = (g == 0) ? B1h : B2h;
        const short* __restrict__ Blp = (g == 0) ? B1l : B2l;

        if (g > 0) __syncthreads();  // At reads (prev MFMA) done; eds reads done
        // stage this relation's edge window into LDS (coalesced int2)
        const int eb0 = rp[row0];
        const int eb1 = rp[min(row0 + 64, nrows)];
        const int ecnt = eb1 - eb0;
        const bool staged = (ecnt < ECAP);   // reserve eds[ecnt] for dummy
        if (staged) {
            for (int i = t; i < ecnt; i += 256) eds[i] = cw[eb0 + i];
            if (t == 0) eds[ecnt] = make_int2(0, 0);  // weight-0 clamp target
        }
        __syncthreads();  // eds ready

        {
            const int r0g = row0 + grp * 8;
            int bnd[9];
            #pragma unroll
            for (int i = 0; i < 9; i++) bnd[i] = rp[min(r0g + i, nrows)];
            #pragma unroll
            for (int p = 0; p < 4; p++) {
                const int A0 = bnd[2 * p],     A1 = bnd[2 * p + 1];
                const int B0 = bnd[2 * p + 1], B1 = bnd[2 * p + 2];
                float4 aA = make_float4(0.f, 0.f, 0.f, 0.f);
                float4 aB = make_float4(0.f, 0.f, 0.f, 0.f);
                // clamp to valid cw entries; empty rows add exact +0.0f terms
                const int lastA = min(max(A1 - 1, A0), NE - 1);
                const int lastB = min(max(B1 - 1, B0), NE - 1);
                int jA = A0, jB = B0;
                while (jA < A1 || jB < B1) {
                    int2 ed[8];
                    if (staged) {
                        #pragma unroll
                        for (int u = 0; u < 4; u++)
                            ed[u] = eds[min(min(jA + u, lastA) - eb0, ecnt)];
                        #pragma unroll
                        for (int u = 0; u < 4; u++)
                            ed[4 + u] = eds[min(min(jB + u, lastB) - eb0, ecnt)];
                    } else {
                        #pragma unroll
                        for (int u = 0; u < 4; u++) ed[u] = cw[min(jA + u, lastA)];
                        #pragma unroll
                        for (int u = 0; u < 4; u++) ed[4 + u] = cw[min(jB + u, lastB)];
                    }
                    float wt[8];
                    #pragma unroll
                    for (int u = 0; u < 4; u++)
                        wt[u] = (jA + u < A1) ? __int_as_float(ed[u].y) : 0.f;
                    #pragma unroll
                    for (int u = 0; u < 4; u++)
                        wt[4 + u] = (jB + u < B1) ? __int_as_float(ed[4 + u].y) : 0.f;
                    float4 v[8];
                    #pragma unroll
                    for (int u = 0; u < 8; u++)
                        v[u] = *(const float4*)(xs + (size_t)ed[u].x * D + l32 * 4);
                    aA.x += wt[0] * v[0].x + wt[1] * v[1].x + wt[2] * v[2].x + wt[3] * v[3].x;
                    aA.y += wt[0] * v[0].y + wt[1] * v[1].y + wt[2] * v[2].y + wt[3] * v[3].y;
                    aA.z += wt[0] * v[0].z + wt[1] * v[1].z + wt[2] * v[2].z + wt[3] * v[3].z;
                    aA.w += wt[0] * v[0].w + wt[1] * v[1].w + wt[2] * v[2].w + wt[3] * v[3].w;
                    aB.x += wt[4] * v[4].x + wt[5] * v[5].x + wt[6] * v[6].x + wt[7] * v[7].x;
                    aB.y += wt[4] * v[4].y + wt[5] * v[5].y + wt[6] * v[6].y + wt[7] * v[7].y;
                    aB.z += wt[4] * v[4].z + wt[5] * v[5].z + wt[6] * v[6].z + wt[7] * v[7].z;
                    aB.w += wt[4] * v[4].w + wt[5] * v[5].w + wt[6] * v[6].w + wt[7] * v[7].w;
                    jA += 4; jB += 4;
                }
                const float invA = 1.0f / (float)max(A1 - A0, 1);
                const float invB = 1.0f / (float)max(B1 - B0, 1);
                aA.x *= invA; aA.y *= invA; aA.z *= invA; aA.w *= invA;
                aB.x *= invB; aB.y *= invB; aB.z *= invB; aB.w *= invB;
                const int lrA = grp * 8 + 2 * p;
                const int lrB = lrA + 1;
                *(float4*)&At[lrA * ASTR + ((l32 ^ ((lrA & 3) << 1)) << 2)] = aA;
                *(float4*)&At[lrB * ASTR + ((l32 ^ ((lrB & 3) << 1)) << 2)] = aB;
            }
        }
        __syncthreads();

        const bfrag* __restrict__ Bh = (const bfrag*)Bhp;
        const bfrag* __restrict__ Bl = (const bfrag*)Blp;
        const int rloc = w * 16 + c;
        const int sw = (rloc & 3) << 1;
        const float* __restrict__ arow_lds = &At[rloc * ASTR];
        #pragma unroll
        for (int kc = 0; kc < 4; kc++) {
            const int g0 = kc * 8 + q * 2;
            float4 a0 = *(const float4*)(arow_lds + ((g0 ^ sw) << 2));
            float4 a1 = *(const float4*)(arow_lds + (((g0 + 1) ^ sw) << 2));
            union { unsigned u[4]; bfrag v; } ahu, alu;
            split2(a0.x, a0.y, ahu.u[0], alu.u[0]);
            split2(a0.z, a0.w, ahu.u[1], alu.u[1]);
            split2(a1.x, a1.y, ahu.u[2], alu.u[2]);
            split2(a1.z, a1.w, ahu.u[3], alu.u[3]);
            bfrag ah = ahu.v, al = alu.v;
            const bfrag* bh = Bh + kc * 512 + lane;
            const bfrag* bl = Bl + kc * 512 + lane;
            #pragma unroll
            for (int nt = 0; nt < 8; nt++) {
                bfrag vh = bh[nt * 64];
                bfrag vl = bl[nt * 64];
                acc[nt] = __builtin_amdgcn_mfma_f32_16x16x32_bf16(ah, vh, acc[nt], 0, 0, 0);
                acc[nt] = __builtin_amdgcn_mfma_f32_16x16x32_bf16(ah, vl, acc[nt], 0, 0, 0);
                acc[nt] = __builtin_amdgcn_mfma_f32_16x16x32_bf16(al, vh, acc[nt], 0, 0, 0);
            }
        }
    }

    // ---- epilogue: collapse h = relu(acc+bias) through C columns in-register.
    float c00[8], c01[8], c10[8], c11[8], bvv[8];
    #pragma unroll
    for (int nt = 0; nt < 8; nt++) {
        float2 v0 = *(const float2*)(Ccol0 + (nt * 16 + c) * 2);
        c00[nt] = v0.x; c01[nt] = v0.y;
        if (NG == 2) {
            float2 v1 = *(const float2*)(Ccol1 + (nt * 16 + c) * 2);
            c10[nt] = v1.x; c11[nt] = v1.y;
        }
        bvv[nt] = bias[nt * 16 + c];
    }
    #pragma unroll
    for (int r = 0; r < 4; r++) {
        int row = row0 + w * 16 + q * 4 + r;
        float s0 = 0.f, s1 = 0.f, t0 = 0.f, t1 = 0.f;
        #pragma unroll
        for (int nt = 0; nt < 8; nt++) {
            float h = fmaxf(acc[nt][r] + bvv[nt], 0.f);
            s0 += h * c00[nt]; s1 += h * c01[nt];
            if (NG == 2) { t0 += h * c10[nt]; t1 += h * c11[nt]; }
        }
        #pragma unroll
        for (int off = 1; off < 16; off <<= 1) {
            s0 += __shfl_xor(s0, off);
            s1 += __shfl_xor(s1, off);
            if (NG == 2) { t0 += __shfl_xor(t0, off); t1 += __shfl_xor(t1, off); }
        }
        if (c == 0 && row < nrows) {
            *(float2*)(zo0 + (size_t)row * 2) = make_float2(s0, s1);
            if (NG == 2) *(float2*)(zo1 + (size_t)row * 2) = make_float2(t0, t1);
        }
    }
}

__global__ __launch_bounds__(256, 4) void fused_all_kernel(
        const float* __restrict__ xapp, const float* __restrict__ xattr,
        const short* __restrict__ PBh, const short* __restrict__ PBl,
        const int* __restrict__ rp0, const int2* __restrict__ cw0,
        const int* __restrict__ rp1, const int2* __restrict__ cw1,
        const int* __restrict__ rp2, const int2* __restrict__ cw2,
        const float* __restrict__ b1, const float* __restrict__ b1s,
        const float* __restrict__ Cs, const float* __restrict__ C2,
        const float* __restrict__ C1,
        float* __restrict__ zs, float* __restrict__ z2, float* __restrict__ za) {
    __shared__ __align__(16) float At[64 * ASTR];
    __shared__ __align__(16) int2 eds[ECAP];
    const size_t MM = (size_t)D * D;
    int b = blockIdx.x;
    if (b < GB_APP) {
        fused_body<2>(xapp, PBh + 2 * MM, PBl + 2 * MM,
                      xattr, rp1, cw1, PBh + 3 * MM, PBl + 3 * MM,
                      xapp,  rp2, cw2, PBh + 4 * MM, PBl + 4 * MM,
                      b1s, Cs, C2, zs, z2, NAPP, b * 64, At, eds);
    } else {
        int bb = b - GB_APP;
        fused_body<1>(xattr, PBh, PBl,
                      xapp, rp0, cw0, PBh + 1 * MM, PBl + 1 * MM,
                      nullptr, nullptr, nullptr, nullptr, nullptr,
                      b1, C1, nullptr, za, nullptr, NATTR, bb * 64, At, eds);
    }
}

// ---------------- final: out[r] = zs[r] + gath1(za)/deg1 + gath2(z2)/deg2 + bconst
__global__ __launch_bounds__(256) void final_out_kernel(
        const float* __restrict__ zs, const float* __restrict__ za,
        const float* __restrict__ z2,
        const int* __restrict__ rp1, const int2* __restrict__ cw1,
        const int* __restrict__ rp2, const int2* __restrict__ cw2,
        const float* __restrict__ bconst, float* __restrict__ out, int n) {
    int r = (blockIdx.x * 256 + threadIdx.x) >> 3;
    int l = threadIdx.x & 7;
    if (r >= n) return;
    int s0 = rp1[r], s1 = rp1[r + 1];
    float q0 = 0.f, q1 = 0.f;
    for (int j = s0 + l; j < s1; j += 8) {
        int2 e = cw1[j];
        float w = __int_as_float(e.y);
        float2 v = *(const float2*)(za + (size_t)e.x * 2);
        q0 += w * v.x; q1 += w * v.y;
    }
    float inv1 = 1.0f / (float)max(s1 - s0, 1);
    float p0 = q0 * inv1, p1 = q1 * inv1;
    s0 = rp2[r]; s1 = rp2[r + 1];
    q0 = 0.f; q1 = 0.f;
    for (int j = s0 + l; j < s1; j += 8) {
        int2 e = cw2[j];
        float w = __int_as_float(e.y);
        float2 v = *(const float2*)(z2 + (size_t)e.x * 2);
        q0 += w * v.x; q1 += w * v.y;
    }
    float inv2 = 1.0f / (float)max(s1 - s0, 1);
    p0 += q0 * inv2; p1 += q1 * inv2;
    #pragma unroll
    for (int off = 1; off < 8; off <<= 1) {
        p0 += __shfl_xor(p0, off);
        p1 += __shfl_xor(p1, off);
    }
    if (l == 0) {
        float2 s = *(const float2*)(zs + (size_t)r * 2);
        out[(size_t)r * 2 + 0] = p0 + s.x + bconst[0];
        out[(size_t)r * 2 + 1] = p1 + s.y + bconst[1];
    }
}

extern "C" void kernel_launch(void* const* d_in, const int* in_sizes, int n_in,
                              void* d_out, int out_size, void* d_ws, size_t ws_size,
                              hipStream_t stream) {
    const float* x_app   = (const float*)d_in[0];
    const float* x_attr  = (const float*)d_in[1];
    const float* ew0     = (const float*)d_in[2];
    const float* ew1     = (const float*)d_in[3];
    const float* ew2     = (const float*)d_in[4];
    const float* Wself1  = (const float*)d_in[5];
    const float* Wneigh1 = (const float*)d_in[6];
    const float* b1      = (const float*)d_in[7];
    const float* Wself2  = (const float*)d_in[8];
    const float* Wneigh2 = (const float*)d_in[9];
    const float* b2      = (const float*)d_in[10];
    const float* Wc      = (const float*)d_in[11];
    const float* bc      = (const float*)d_in[12];
    const int* src0 = (const int*)d_in[13];
    const int* dst0 = (const int*)d_in[14];
    const int* src1 = (const int*)d_in[15];
    const int* dst1 = (const int*)d_in[16];
    const int* src2 = (const int*)d_in[17];
    const int* dst2 = (const int*)d_in[18];
    float* out = (float*)d_out;

    // ---- workspace layout (4-byte units; cw blocks start at even offsets) ----
    float* ws = (float*)d_ws;
    float* h_attr = ws;                                  // NATTR*D (unused)
    float* h_app  = h_attr + (size_t)NATTR * D;          // NAPP*D (unused)
    float* b1s    = h_app  + (size_t)NAPP * D;           // D
    float* b2s    = b1s + D;                             // D
    float* za     = b2s + D;                             // NATTR*2
    float* zsv    = za + (size_t)NATTR * 2;              // NAPP*2
    float* z2v    = zsv + (size_t)NAPP * 2;              // NAPP*2
    float* Cs     = z2v + (size_t)NAPP * 2;              // 256
    float* C1     = Cs + 256;                            // 256
    float* C2     = C1 + 256;                            // 256
    float* bconst = C2 + 256;                            // 4
    int* cur  = (int*)(bconst + 4);                      // SNB*SCHUNK
    int* cur0 = cur;
    int* cur1 = cur0 + NATTR;
    int* cur2 = cur1 + NAPP;
    int* rp0  = cur + SNB * SCHUNK;                      // NATTR+4
    int* rp1  = rp0 + NATTR + 4;                         // NAPP+4
    int* rp2  = rp1 + NAPP + 4;                          // NAPP+4
    int* bsum = rp2 + NAPP + 4;                          // 256
    int* boff = bsum + 256;                              // 256
    int2* cw0 = (int2*)(boff + 256);                     // NE int2
    int2* cw1 = cw0 + NE;                                // NE int2
    int2* cw2 = cw1 + NE;                                // NE int2
    short* PBh = (short*)(cw2 + NE);                     // 8*D*D shorts
    short* PBl = PBh + (size_t)8 * D * D;                // 8*D*D shorts

    hipMemsetAsync(cur, 0, (size_t)SNB * SCHUNK * sizeof(int), stream);

    pack_kernel<<<9, 256, 0, stream>>>(Wself1, Wneigh1, Wself2, Wneigh2,
                                       b1, b2, Wc, bc, PBh, PBl, b1s, b2s,
                                       Cs, C1, C2, bconst);

    // ---- CSR build ----
    hist3_kernel<<<3 * EGRID, 256, 0, stream>>>(dst0, dst1, dst2, cur0, cur1, cur2);
    scan_partial_kernel<<<SNB, 256, 0, stream>>>(cur, bsum);
    scan_offsets_kernel<<<1, 256, 0, stream>>>(bsum, boff, rp0, rp1, rp2);
    scan_final_kernel<<<SNB, 256, 0, stream>>>(cur, boff, rp0, rp1, rp2);
    scatter3_kernel<<<3 * EGRID, 256, 0, stream>>>(
        src0, dst0, ew0, cur0, cw0,
        src1, dst1, ew1, cur1, cw1,
        src2, dst2, ew2, cur2, cw2);

    // ---- layer 1 + collapsed layer-2 projections, one launch ----
    fused_all_kernel<<<GB_APP + GB_ATTR, 256, 0, stream>>>(
        x_app, x_attr, PBh, PBl,
        rp0, cw0, rp1, cw1, rp2, cw2,
        b1, b1s, Cs, C2, C1, zsv, z2v, za);

    // ---- final gather over collapsed 2-wide features ----
    final_out_kernel<<<((size_t)NAPP * 8 + 255) / 256, 256, 0, stream>>>(
        zsv, za, z2v, rp1, cw1, rp2, cw2, bconst, out, NAPP);
}

// Round 9
// 421.307 us; speedup vs baseline: 3.3759x; 1.1640x over previous
//
#include <hip/hip_runtime.h>

#define NAPP  100000
#define NATTR 50000
#define NE    500000
#define D     128
#define NTOT  (NATTR + 2 * NAPP)
#define SCHUNK 1024
#define SNB   ((NTOT + SCHUNK - 1) / SCHUNK)
#define EG4   ((NE / 4 + 255) / 256)
#define GB_APP  ((NAPP + 63) / 64)
#define GB_ATTR ((NATTR + 63) / 64)
#define ECAP  1024

typedef __attribute__((ext_vector_type(8))) short bfrag;
typedef __attribute__((ext_vector_type(4))) float f32x4;

__device__ __forceinline__ short bf16_rn(float x) {
    union { float f; unsigned u; } a; a.f = x;
    unsigned r = (a.u + 0x7fffu + ((a.u >> 16) & 1u)) >> 16;
    return (short)r;
}
__device__ __forceinline__ float bf16_to_f(short s) {
    union { float f; unsigned u; } a;
    a.u = ((unsigned)(unsigned short)s) << 16;
    return a.f;
}

// split two floats into packed bf16-hi pair and bf16-lo (residual) pair.
__device__ __forceinline__ void split2(float x, float y, unsigned& hw, unsigned& lw) {
    union { float f; unsigned u; } ax, ay;
    ax.f = x; ay.f = y;
    unsigned hx = (ax.u + 0x7fffu + ((ax.u >> 16) & 1u)) >> 16;
    unsigned hy = (ay.u + 0x7fffu + ((ay.u >> 16) & 1u)) >> 16;
    union { unsigned u; float f; } fx, fy;
    fx.u = hx << 16; fy.u = hy << 16;
    union { float f; unsigned u; } rx, ry;
    rx.f = x - fx.f; ry.f = y - fy.f;
    unsigned lx = (rx.u + 0x7fffu + ((rx.u >> 16) & 1u)) >> 16;
    unsigned ly = (ry.u + 0x7fffu + ((ry.u >> 16) & 1u)) >> 16;
    hw = (hy << 16) | (hx & 0xffffu);
    lw = (ly << 16) | (lx & 0xffffu);
}

// ---------------- histogram over 3 relations, 4 edges/thread, rank-recording --
// The atomic's return value IS the edge's within-row rank; record it so the
// scatter pass needs no atomics at all.
__global__ __launch_bounds__(256) void hist3_kernel(
        const int* __restrict__ d0, const int* __restrict__ d1, const int* __restrict__ d2,
        int* __restrict__ h0, int* __restrict__ h1, int* __restrict__ h2,
        int* __restrict__ r0, int* __restrict__ r1, int* __restrict__ r2) {
    int b = blockIdx.x;
    int rel = b / EG4;
    int i4 = (b - rel * EG4) * 256 + threadIdx.x;
    if (i4 * 4 >= NE) return;
    const int* dst = (rel == 0) ? d0 : (rel == 1) ? d1 : d2;
    int* h = (rel == 0) ? h0 : (rel == 1) ? h1 : h2;
    int* rk = (rel == 0) ? r0 : (rel == 1) ? r1 : r2;
    int4 d = *((const int4*)dst + i4);
    int4 r;
    r.x = atomicAdd(&h[d.x], 1);
    r.y = atomicAdd(&h[d.y], 1);
    r.z = atomicAdd(&h[d.z], 1);
    r.w = atomicAdd(&h[d.w], 1);
    *((int4*)rk + i4) = r;
}

// ---------------- scan phase A ----------------
__global__ __launch_bounds__(256) void scan_partial_kernel(const int* __restrict__ cur,
                                                           int* __restrict__ bsum) {
    int b = blockIdx.x, t = threadIdx.x;
    int4 v = *((const int4*)(cur + b * SCHUNK) + t);
    int s = v.x + v.y + v.z + v.w;
    __shared__ int sd[256];
    sd[t] = s;
    __syncthreads();
    for (int off = 128; off > 0; off >>= 1) {
        if (t < off) sd[t] += sd[t + off];
        __syncthreads();
    }
    if (t == 0) bsum[b] = sd[0];
}

// ---------------- scan phase B ----------------
__global__ __launch_bounds__(256) void scan_offsets_kernel(const int* __restrict__ bsum,
        int* __restrict__ boff, int* __restrict__ rp0, int* __restrict__ rp1,
        int* __restrict__ rp2) {
    int t = threadIdx.x;
    int v = (t < SNB) ? bsum[t] : 0;
    __shared__ int sd[256];
    sd[t] = v;
    __syncthreads();
    for (int off = 1; off < 256; off <<= 1) {
        int u = (t >= off) ? sd[t - off] : 0;
        __syncthreads();
        sd[t] += u;
        __syncthreads();
    }
    boff[t] = sd[t] - v;
    if (t == 0) { rp0[NATTR] = NE; rp1[NAPP] = NE; rp2[NAPP] = NE; }
}

// ---------------- scan phase C (writes rp only; cur no longer needed) -------
__global__ __launch_bounds__(256) void scan_final_kernel(const int* __restrict__ cur,
        const int* __restrict__ boff, int* __restrict__ rp0, int* __restrict__ rp1,
        int* __restrict__ rp2) {
    int b = blockIdx.x, t = threadIdx.x;
    int base = b * SCHUNK + t * 4;
    int4 v = *(const int4*)(cur + base);
    int s = v.x + v.y + v.z + v.w;
    __shared__ int sd[256];
    sd[t] = s;
    __syncthreads();
    for (int off = 1; off < 256; off <<= 1) {
        int u = (t >= off) ? sd[t - off] : 0;
        __syncthreads();
        sd[t] += u;
        __syncthreads();
    }
    int pre = boff[b] + sd[t] - s;
    int ex[4];
    ex[0] = pre;
    ex[1] = ex[0] + v.x;
    ex[2] = ex[1] + v.y;
    ex[3] = ex[2] + v.z;
    #pragma unroll
    for (int i = 0; i < 4; i++) {
        int idx = base + i;
        if (idx < NTOT) {
            int* rp; int loc; int rbase;
            if (idx < NATTR)             { rp = rp0; loc = idx;                 rbase = 0; }
            else if (idx < NATTR + NAPP) { rp = rp1; loc = idx - NATTR;        rbase = NE; }
            else                         { rp = rp2; loc = idx - NATTR - NAPP; rbase = 2 * NE; }
            rp[loc] = ex[i] - rbase;
        }
    }
}

// ---------------- scatter, rank-based (NO atomics), 4 edges/thread ----------
__global__ __launch_bounds__(256) void scatter3_kernel(
        const int* __restrict__ s0, const int* __restrict__ d0, const float* __restrict__ e0,
        const int* __restrict__ r0, const int* __restrict__ rp0, int2* __restrict__ cw0,
        const int* __restrict__ s1, const int* __restrict__ d1, const float* __restrict__ e1,
        const int* __restrict__ r1, const int* __restrict__ rp1, int2* __restrict__ cw1,
        const int* __restrict__ s2, const int* __restrict__ d2, const float* __restrict__ e2,
        const int* __restrict__ r2, const int* __restrict__ rp2, int2* __restrict__ cw2) {
    int b = blockIdx.x;
    int rel = b / EG4;
    int i4 = (b - rel * EG4) * 256 + threadIdx.x;
    if (i4 * 4 >= NE) return;
    const int* src; const int* dst; const float* ew; const int* rk; const int* rp; int2* cw;
    if (rel == 0)      { src = s0; dst = d0; ew = e0; rk = r0; rp = rp0; cw = cw0; }
    else if (rel == 1) { src = s1; dst = d1; ew = e1; rk = r1; rp = rp1; cw = cw1; }
    else               { src = s2; dst = d2; ew = e2; rk = r2; rp = rp2; cw = cw2; }
    int4 s = *((const int4*)src + i4);
    int4 d = *((const int4*)dst + i4);
    float4 e = *((const float4*)ew + i4);
    int4 r = *((const int4*)rk + i4);
    cw[rp[d.x] + r.x] = make_int2(s.x, __float_as_int(e.x));
    cw[rp[d.y] + r.y] = make_int2(s.y, __float_as_int(e.y));
    cw[rp[d.z] + r.z] = make_int2(s.z, __float_as_int(e.z));
    cw[rp[d.w] + r.w] = make_int2(s.w, __float_as_int(e.w));
}

// ---------------- pack weights + layer-2 collapsed constants ----------------
__global__ __launch_bounds__(256) void pack_kernel(
        const float* __restrict__ Wself1, const float* __restrict__ Wneigh1,
        const float* __restrict__ Wself2, const float* __restrict__ Wneigh2,
        const float* __restrict__ b1, const float* __restrict__ b2,
        const float* __restrict__ Wc, const float* __restrict__ bc,
        short* __restrict__ PBh, short* __restrict__ PBl,
        float* __restrict__ b1s, float* __restrict__ b2s,
        float* __restrict__ Cs, float* __restrict__ C1, float* __restrict__ C2,
        float* __restrict__ bconst) {
    int m = blockIdx.x;
    if (m == 8) {
        int tid = threadIdx.x;
        int k = tid >> 1, j = tid & 1;
        const float* Wn1 = Wneigh2 + D * D;
        const float* Wn2 = Wneigh2 + 2 * D * D;
        const float* Ws1 = Wself2 + D * D;
        const float* Ws2 = Wself2 + 2 * D * D;
        float ss = 0.f, s1 = 0.f, s2 = 0.f;
        for (int tt = 0; tt < D; tt++) {
            float wc = Wc[tt * 2 + j];
            ss += (Ws1[k * D + tt] + Ws2[k * D + tt]) * wc;
            s1 += Wn1[k * D + tt] * wc;
            s2 += Wn2[k * D + tt] * wc;
        }
        Cs[tid] = ss; C1[tid] = s1; C2[tid] = s2;
        if (tid < 2) {
            float s = bc[tid];
            for (int tt = 0; tt < D; tt++)
                s += (b2[D + tt] + b2[2 * D + tt]) * Wc[tt * 2 + tid];
            bconst[tid] = s;
        }
        return;
    }
    const float* srcA; const float* srcB = nullptr;
    switch (m) {
        case 0: srcA = Wself1; break;
        case 1: srcA = Wneigh1; break;
        case 2: srcA = Wself1 + D * D; srcB = Wself1 + 2 * D * D; break;
        case 3: srcA = Wneigh1 + D * D; break;
        case 4: srcA = Wneigh1 + 2 * D * D; break;
        case 5: srcA = Wself2 + D * D; srcB = Wself2 + 2 * D * D; break;
        case 6: srcA = Wneigh2 + D * D; break;
        default: srcA = Wneigh2 + 2 * D * D; break;
    }
    short* oh = PBh + (size_t)m * D * D;
    short* ol = PBl + (size_t)m * D * D;
    for (int i = threadIdx.x; i < D * D; i += 256) {
        int k = i >> 7, n = i & 127;
        float v = srcA[i];
        if (srcB) v += srcB[i];
        short hi = bf16_rn(v);
        short lo = bf16_rn(v - bf16_to_f(hi));
        int kc = k >> 5, q = (k >> 3) & 3, j = k & 7, nt = n >> 4, c = n & 15;
        int pos = (((kc * 8 + nt) * 64) + q * 16 + c) * 8 + j;
        oh[pos] = hi;
        ol[pos] = lo;
    }
    if (m == 0 && threadIdx.x < D) {
        int t = threadIdx.x;
        b1s[t] = b1[D + t] + b1[2 * D + t];
        b2s[t] = b2[D + t] + b2[2 * D + t];
    }
}

// ---------------- fused gather + MFMA node update + collapsed classifier ----
// (round-8 verified body, unchanged: LDS edge staging with dummy clamp slot)
#define ASTR 128
template<int NG>
__device__ __forceinline__ void fused_body(
        const float* __restrict__ in0, const short* __restrict__ B0h, const short* __restrict__ B0l,
        const float* __restrict__ x1, const int* __restrict__ rp1, const int2* __restrict__ cw1,
        const short* __restrict__ B1h, const short* __restrict__ B1l,
        const float* __restrict__ x2, const int* __restrict__ rp2, const int2* __restrict__ cw2,
        const short* __restrict__ B2h, const short* __restrict__ B2l,
        const float* __restrict__ bias,
        const float* __restrict__ Ccol0, const float* __restrict__ Ccol1,
        float* __restrict__ zo0, float* __restrict__ zo1,
        int nrows, int row0, float* At, int2* eds) {
    const int t = threadIdx.x;
    const int w = t >> 6, lane = t & 63;
    const int q = lane >> 4, c = lane & 15;
    const int myrow = row0 + w * 16 + c;
    const int arow = min(myrow, nrows - 1);

    f32x4 acc[8];
    #pragma unroll
    for (int nt = 0; nt < 8; nt++) acc[nt] = (f32x4){0.f, 0.f, 0.f, 0.f};

    // ---- direct (self) source: global -> reg fragments ----
    {
        const float* __restrict__ arp = in0 + (size_t)arow * D;
        const bfrag* __restrict__ Bh = (const bfrag*)B0h;
        const bfrag* __restrict__ Bl = (const bfrag*)B0l;
        #pragma unroll
        for (int kc = 0; kc < 4; kc++) {
            float4 a0 = *(const float4*)(arp + kc * 32 + q * 8);
            float4 a1 = *(const float4*)(arp + kc * 32 + q * 8 + 4);
            union { unsigned u[4]; bfrag v; } ahu, alu;
            split2(a0.x, a0.y, ahu.u[0], alu.u[0]);
            split2(a0.z, a0.w, ahu.u[1], alu.u[1]);
            split2(a1.x, a1.y, ahu.u[2], alu.u[2]);
            split2(a1.z, a1.w, ahu.u[3], alu.u[3]);
            bfrag ah = ahu.v, al = alu.v;
            const bfrag* bh = Bh + kc * 512 + lane;
            const bfrag* bl = Bl + kc * 512 + lane;
            #pragma unroll
            for (int nt = 0; nt < 8; nt++) {
                bfrag vh = bh[nt * 64];
                bfrag vl = bl[nt * 64];
                acc[nt] = __builtin_amdgcn_mfma_f32_16x16x32_bf16(ah, vh, acc[nt], 0, 0, 0);
                acc[nt] = __builtin_amdgcn_mfma_f32_16x16x32_bf16(ah, vl, acc[nt], 0, 0, 0);
                acc[nt] = __builtin_amdgcn_mfma_f32_16x16x32_bf16(al, vh, acc[nt], 0, 0, 0);
            }
        }
    }

    // ---- gathered sources: stage edges -> LDS, gather -> LDS, MFMA ----
    const int grp = t >> 5, l32 = t & 31;
    #pragma unroll
    for (int g = 0; g < NG; g++) {
        const float* __restrict__ xs = (g == 0) ? x1 : x2;
        const int* __restrict__ rp   = (g == 0) ? rp1 : rp2;
        const int2* __restrict__ cw  = (g == 0) ? cw1 : cw2;
        const short* __restrict__ Bhp = (g == 0) ? B1h : B2h;
        const short* __restrict__ Blp = (g == 0) ? B1l : B2l;

        if (g > 0) __syncthreads();
        const int eb0 = rp[row0];
        const int eb1 = rp[min(row0 + 64, nrows)];
        const int ecnt = eb1 - eb0;
        const bool staged = (ecnt < ECAP);
        if (staged) {
            for (int i = t; i < ecnt; i += 256) eds[i] = cw[eb0 + i];
            if (t == 0) eds[ecnt] = make_int2(0, 0);
        }
        __syncthreads();

        {
            const int r0g = row0 + grp * 8;
            int bnd[9];
            #pragma unroll
            for (int i = 0; i < 9; i++) bnd[i] = rp[min(r0g + i, nrows)];
            #pragma unroll
            for (int p = 0; p < 4; p++) {
                const int A0 = bnd[2 * p],     A1 = bnd[2 * p + 1];
                const int B0 = bnd[2 * p + 1], B1 = bnd[2 * p + 2];
                float4 aA = make_float4(0.f, 0.f, 0.f, 0.f);
                float4 aB = make_float4(0.f, 0.f, 0.f, 0.f);
                const int lastA = min(max(A1 - 1, A0), NE - 1);
                const int lastB = min(max(B1 - 1, B0), NE - 1);
                int jA = A0, jB = B0;
                while (jA < A1 || jB < B1) {
                    int2 ed[8];
                    if (staged) {
                        #pragma unroll
                        for (int u = 0; u < 4; u++)
                            ed[u] = eds[min(min(jA + u, lastA) - eb0, ecnt)];
                        #pragma unroll
                        for (int u = 0; u < 4; u++)
                            ed[4 + u] = eds[min(min(jB + u, lastB) - eb0, ecnt)];
                    } else {
                        #pragma unroll
                        for (int u = 0; u < 4; u++) ed[u] = cw[min(jA + u, lastA)];
                        #pragma unroll
                        for (int u = 0; u < 4; u++) ed[4 + u] = cw[min(jB + u, lastB)];
                    }
                    float wt[8];
                    #pragma unroll
                    for (int u = 0; u < 4; u++)
                        wt[u] = (jA + u < A1) ? __int_as_float(ed[u].y) : 0.f;
                    #pragma unroll
                    for (int u = 0; u < 4; u++)
                        wt[4 + u] = (jB + u < B1) ? __int_as_float(ed[4 + u].y) : 0.f;
                    float4 v[8];
                    #pragma unroll
                    for (int u = 0; u < 8; u++)
                        v[u] = *(const float4*)(xs + (size_t)ed[u].x * D + l32 * 4);
                    aA.x += wt[0] * v[0].x + wt[1] * v[1].x + wt[2] * v[2].x + wt[3] * v[3].x;
                    aA.y += wt[0] * v[0].y + wt[1] * v[1].y + wt[2] * v[2].y + wt[3] * v[3].y;
                    aA.z += wt[0] * v[0].z + wt[1] * v[1].z + wt[2] * v[2].z + wt[3] * v[3].z;
                    aA.w += wt[0] * v[0].w + wt[1] * v[1].w + wt[2] * v[2].w + wt[3] * v[3].w;
                    aB.x += wt[4] * v[4].x + wt[5] * v[5].x + wt[6] * v[6].x + wt[7] * v[7].x;
                    aB.y += wt[4] * v[4].y + wt[5] * v[5].y + wt[6] * v[6].y + wt[7] * v[7].y;
                    aB.z += wt[4] * v[4].z + wt[5] * v[5].z + wt[6] * v[6].z + wt[7] * v[7].z;
                    aB.w += wt[4] * v[4].w + wt[5] * v[5].w + wt[6] * v[6].w + wt[7] * v[7].w;
                    jA += 4; jB += 4;
                }
                const float invA = 1.0f / (float)max(A1 - A0, 1);
                const float invB = 1.0f / (float)max(B1 - B0, 1);
                aA.x *= invA; aA.y *= invA; aA.z *= invA; aA.w *= invA;
                aB.x *= invB; aB.y *= invB; aB.z *= invB; aB.w *= invB;
                const int lrA = grp * 8 + 2 * p;
                const int lrB = lrA + 1;
                *(float4*)&At[lrA * ASTR + ((l32 ^ ((lrA & 3) << 1)) << 2)] = aA;
                *(float4*)&At[lrB * ASTR + ((l32 ^ ((lrB & 3) << 1)) << 2)] = aB;
            }
        }
        __syncthreads();

        const bfrag* __restrict__ Bh = (const bfrag*)Bhp;
        const bfrag* __restrict__ Bl = (const bfrag*)Blp;
        const int rloc = w * 16 + c;
        const int sw = (rloc & 3) << 1;
        const float* __restrict__ arow_lds = &At[rloc * ASTR];
        #pragma unroll
        for (int kc = 0; kc < 4; kc++) {
            const int g0 = kc * 8 + q * 2;
            float4 a0 = *(const float4*)(arow_lds + ((g0 ^ sw) << 2));
            float4 a1 = *(const float4*)(arow_lds + (((g0 + 1) ^ sw) << 2));
            union { unsigned u[4]; bfrag v; } ahu, alu;
            split2(a0.x, a0.y, ahu.u[0], alu.u[0]);
            split2(a0.z, a0.w, ahu.u[1], alu.u[1]);
            split2(a1.x, a1.y, ahu.u[2], alu.u[2]);
            split2(a1.z, a1.w, ahu.u[3], alu.u[3]);
            bfrag ah = ahu.v, al = alu.v;
            const bfrag* bh = Bh + kc * 512 + lane;
            const bfrag* bl = Bl + kc * 512 + lane;
            #pragma unroll
            for (int nt = 0; nt < 8; nt++) {
                bfrag vh = bh[nt * 64];
                bfrag vl = bl[nt * 64];
                acc[nt] = __builtin_amdgcn_mfma_f32_16x16x32_bf16(ah, vh, acc[nt], 0, 0, 0);
                acc[nt] = __builtin_amdgcn_mfma_f32_16x16x32_bf16(ah, vl, acc[nt], 0, 0, 0);
                acc[nt] = __builtin_amdgcn_mfma_f32_16x16x32_bf16(al, vh, acc[nt], 0, 0, 0);
            }
        }
    }

    // ---- epilogue: collapse h = relu(acc+bias) through C columns in-register.
    float c00[8], c01[8], c10[8], c11[8], bvv[8];
    #pragma unroll
    for (int nt = 0; nt < 8; nt++) {
        float2 v0 = *(const float2*)(Ccol0 + (nt * 16 + c) * 2);
        c00[nt] = v0.x; c01[nt] = v0.y;
        if (NG == 2) {
            float2 v1 = *(const float2*)(Ccol1 + (nt * 16 + c) * 2);
            c10[nt] = v1.x; c11[nt] = v1.y;
        }
        bvv[nt] = bias[nt * 16 + c];
    }
    #pragma unroll
    for (int r = 0; r < 4; r++) {
        int row = row0 + w * 16 + q * 4 + r;
        float s0 = 0.f, s1 = 0.f, t0 = 0.f, t1 = 0.f;
        #pragma unroll
        for (int nt = 0; nt < 8; nt++) {
            float h = fmaxf(acc[nt][r] + bvv[nt], 0.f);
            s0 += h * c00[nt]; s1 += h * c01[nt];
            if (NG == 2) { t0 += h * c10[nt]; t1 += h * c11[nt]; }
        }
        #pragma unroll
        for (int off = 1; off < 16; off <<= 1) {
            s0 += __shfl_xor(s0, off);
            s1 += __shfl_xor(s1, off);
            if (NG == 2) { t0 += __shfl_xor(t0, off); t1 += __shfl_xor(t1, off); }
        }
        if (c == 0 && row < nrows) {
            *(float2*)(zo0 + (size_t)row * 2) = make_float2(s0, s1);
            if (NG == 2) *(float2*)(zo1 + (size_t)row * 2) = make_float2(t0, t1);
        }
    }
}

__global__ __launch_bounds__(256, 4) void fused_all_kernel(
        const float* __restrict__ xapp, const float* __restrict__ xattr,
        const short* __restrict__ PBh, const short* __restrict__ PBl,
        const int* __restrict__ rp0, const int2* __restrict__ cw0,
        const int* __restrict__ rp1, const int2* __restrict__ cw1,
        const int* __restrict__ rp2, const int2* __restrict__ cw2,
        const float* __restrict__ b1, const float* __restrict__ b1s,
        const float* __restrict__ Cs, const float* __restrict__ C2,
        const float* __restrict__ C1,
        float* __restrict__ zs, float* __restrict__ z2, float* __restrict__ za) {
    __shared__ __align__(16) float At[64 * ASTR];
    __shared__ __align__(16) int2 eds[ECAP];
    const size_t MM = (size_t)D * D;
    int b = blockIdx.x;
    if (b < GB_APP) {
        fused_body<2>(xapp, PBh + 2 * MM, PBl + 2 * MM,
                      xattr, rp1, cw1, PBh + 3 * MM, PBl + 3 * MM,
                      xapp,  rp2, cw2, PBh + 4 * MM, PBl + 4 * MM,
                      b1s, Cs, C2, zs, z2, NAPP, b * 64, At, eds);
    } else {
        int bb = b - GB_APP;
        fused_body<1>(xattr, PBh, PBl,
                      xapp, rp0, cw0, PBh + 1 * MM, PBl + 1 * MM,
                      nullptr, nullptr, nullptr, nullptr, nullptr,
                      b1, C1, nullptr, za, nullptr, NATTR, bb * 64, At, eds);
    }
}

// ---------------- final: 4 lanes/row (mean degree ~5; 8 lanes left most idle)
__global__ __launch_bounds__(256) void final_out_kernel(
        const float* __restrict__ zs, const float* __restrict__ za,
        const float* __restrict__ z2,
        const int* __restrict__ rp1, const int2* __restrict__ cw1,
        const int* __restrict__ rp2, const int2* __restrict__ cw2,
        const float* __restrict__ bconst, float* __restrict__ out, int n) {
    int r = (blockIdx.x * 256 + threadIdx.x) >> 2;
    int l = threadIdx.x & 3;
    if (r >= n) return;
    int s0 = rp1[r], s1 = rp1[r + 1];
    float q0 = 0.f, q1 = 0.f;
    for (int j = s0 + l; j < s1; j += 4) {
        int2 e = cw1[j];
        float w = __int_as_float(e.y);
        float2 v = *(const float2*)(za + (size_t)e.x * 2);
        q0 += w * v.x; q1 += w * v.y;
    }
    float inv1 = 1.0f / (float)max(s1 - s0, 1);
    float p0 = q0 * inv1, p1 = q1 * inv1;
    s0 = rp2[r]; s1 = rp2[r + 1];
    q0 = 0.f; q1 = 0.f;
    for (int j = s0 + l; j < s1; j += 4) {
        int2 e = cw2[j];
        float w = __int_as_float(e.y);
        float2 v = *(const float2*)(z2 + (size_t)e.x * 2);
        q0 += w * v.x; q1 += w * v.y;
    }
    float inv2 = 1.0f / (float)max(s1 - s0, 1);
    p0 += q0 * inv2; p1 += q1 * inv2;
    #pragma unroll
    for (int off = 1; off < 4; off <<= 1) {
        p0 += __shfl_xor(p0, off);
        p1 += __shfl_xor(p1, off);
    }
    if (l == 0) {
        float2 s = *(const float2*)(zs + (size_t)r * 2);
        out[(size_t)r * 2 + 0] = p0 + s.x + bconst[0];
        out[(size_t)r * 2 + 1] = p1 + s.y + bconst[1];
    }
}

extern "C" void kernel_launch(void* const* d_in, const int* in_sizes, int n_in,
                              void* d_out, int out_size, void* d_ws, size_t ws_size,
                              hipStream_t stream) {
    const float* x_app   = (const float*)d_in[0];
    const float* x_attr  = (const float*)d_in[1];
    const float* ew0     = (const float*)d_in[2];
    const float* ew1     = (const float*)d_in[3];
    const float* ew2     = (const float*)d_in[4];
    const float* Wself1  = (const float*)d_in[5];
    const float* Wneigh1 = (const float*)d_in[6];
    const float* b1      = (const float*)d_in[7];
    const float* Wself2  = (const float*)d_in[8];
    const float* Wneigh2 = (const float*)d_in[9];
    const float* b2      = (const float*)d_in[10];
    const float* Wc      = (const float*)d_in[11];
    const float* bc      = (const float*)d_in[12];
    const int* src0 = (const int*)d_in[13];
    const int* dst0 = (const int*)d_in[14];
    const int* src1 = (const int*)d_in[15];
    const int* dst1 = (const int*)d_in[16];
    const int* src2 = (const int*)d_in[17];
    const int* dst2 = (const int*)d_in[18];
    float* out = (float*)d_out;

    // ---- workspace layout (4-byte units; cw blocks start at even offsets) ----
    float* ws = (float*)d_ws;
    float* h_attr = ws;                                  // NATTR*D (reused: ranks)
    float* h_app  = h_attr + (size_t)NATTR * D;          // NAPP*D (unused)
    float* b1s    = h_app  + (size_t)NAPP * D;           // D
    float* b2s    = b1s + D;                             // D
    float* za     = b2s + D;                             // NATTR*2
    float* zsv    = za + (size_t)NATTR * 2;              // NAPP*2
    float* z2v    = zsv + (size_t)NAPP * 2;              // NAPP*2
    float* Cs     = z2v + (size_t)NAPP * 2;              // 256
    float* C1     = Cs + 256;                            // 256
    float* C2     = C1 + 256;                            // 256
    float* bconst = C2 + 256;                            // 4
    int* cur  = (int*)(bconst + 4);                      // SNB*SCHUNK
    int* cur0 = cur;
    int* cur1 = cur0 + NATTR;
    int* cur2 = cur1 + NAPP;
    int* rp0  = cur + SNB * SCHUNK;                      // NATTR+4
    int* rp1  = rp0 + NATTR + 4;                         // NAPP+4
    int* rp2  = rp1 + NAPP + 4;                          // NAPP+4
    int* bsum = rp2 + NAPP + 4;                          // 256
    int* boff = bsum + 256;                              // 256
    int2* cw0 = (int2*)(boff + 256);                     // NE int2
    int2* cw1 = cw0 + NE;                                // NE int2
    int2* cw2 = cw1 + NE;                                // NE int2
    short* PBh = (short*)(cw2 + NE);                     // 8*D*D shorts
    short* PBl = PBh + (size_t)8 * D * D;                // 8*D*D shorts
    // rank arrays live in the dead h_attr slot (6 MB << 25.6 MB)
    int* rank0 = (int*)h_attr;                           // NE
    int* rank1 = rank0 + NE;                             // NE
    int* rank2 = rank1 + NE;                             // NE

    hipMemsetAsync(cur, 0, (size_t)SNB * SCHUNK * sizeof(int), stream);

    pack_kernel<<<9, 256, 0, stream>>>(Wself1, Wneigh1, Wself2, Wneigh2,
                                       b1, b2, Wc, bc, PBh, PBl, b1s, b2s,
                                       Cs, C1, C2, bconst);

    // ---- CSR build (rank-recording; scatter is atomic-free) ----
    hist3_kernel<<<3 * EG4, 256, 0, stream>>>(dst0, dst1, dst2, cur0, cur1, cur2,
                                              rank0, rank1, rank2);
    scan_partial_kernel<<<SNB, 256, 0, stream>>>(cur, bsum);
    scan_offsets_kernel<<<1, 256, 0, stream>>>(bsum, boff, rp0, rp1, rp2);
    scan_final_kernel<<<SNB, 256, 0, stream>>>(cur, boff, rp0, rp1, rp2);
    scatter3_kernel<<<3 * EG4, 256, 0, stream>>>(
        src0, dst0, ew0, rank0, rp0, cw0,
        src1, dst1, ew1, rank1, rp1, cw1,
        src2, dst2, ew2, rank2, rp2, cw2);

    // ---- layer 1 + collapsed layer-2 projections, one launch ----
    fused_all_kernel<<<GB_APP + GB_ATTR, 256, 0, stream>>>(
        x_app, x_attr, PBh, PBl,
        rp0, cw0, rp1, cw1, rp2, cw2,
        b1, b1s, Cs, C2, C1, zsv, z2v, za);

    // ---- final gather over collapsed 2-wide features ----
    final_out_kernel<<<((size_t)NAPP * 4 + 255) / 256, 256, 0, stream>>>(
        zsv, za, z2v, rp1, cw1, rp2, cw2, bconst, out, NAPP);
}

// Round 10
// 413.931 us; speedup vs baseline: 3.4360x; 1.0178x over previous
//
#include <hip/hip_runtime.h>

#define NAPP  100000
#define NATTR 50000
#define NE    500000
#define D     128
#define NTOT  (NATTR + 2 * NAPP)
#define SCHUNK 1024
#define SNB   ((NTOT + SCHUNK - 1) / SCHUNK)
#define EG8   ((NE / 8 + 255) / 256)
#define GB_APP  ((NAPP + 63) / 64)
#define GB_ATTR ((NATTR + 63) / 64)
#define ECAP  1024
#define ZERO_B 64

typedef __attribute__((ext_vector_type(8))) short bfrag;
typedef __attribute__((ext_vector_type(4))) float f32x4;

__device__ __forceinline__ short bf16_rn(float x) {
    union { float f; unsigned u; } a; a.f = x;
    unsigned r = (a.u + 0x7fffu + ((a.u >> 16) & 1u)) >> 16;
    return (short)r;
}
__device__ __forceinline__ float bf16_to_f(short s) {
    union { float f; unsigned u; } a;
    a.u = ((unsigned)(unsigned short)s) << 16;
    return a.f;
}

// split two floats into packed bf16-hi pair and bf16-lo (residual) pair.
__device__ __forceinline__ void split2(float x, float y, unsigned& hw, unsigned& lw) {
    union { float f; unsigned u; } ax, ay;
    ax.f = x; ay.f = y;
    unsigned hx = (ax.u + 0x7fffu + ((ax.u >> 16) & 1u)) >> 16;
    unsigned hy = (ay.u + 0x7fffu + ((ay.u >> 16) & 1u)) >> 16;
    union { unsigned u; float f; } fx, fy;
    fx.u = hx << 16; fy.u = hy << 16;
    union { float f; unsigned u; } rx, ry;
    rx.f = x - fx.f; ry.f = y - fy.f;
    unsigned lx = (rx.u + 0x7fffu + ((rx.u >> 16) & 1u)) >> 16;
    unsigned ly = (ry.u + 0x7fffu + ((ry.u >> 16) & 1u)) >> 16;
    hw = (hy << 16) | (hx & 0xffffu);
    lw = (ly << 16) | (lx & 0xffffu);
}

// ---------------- histogram, 8 edges/thread, short rank-recording ----------
__global__ __launch_bounds__(256) void hist3_kernel(
        const int* __restrict__ d0, const int* __restrict__ d1, const int* __restrict__ d2,
        int* __restrict__ h0, int* __restrict__ h1, int* __restrict__ h2,
        short* __restrict__ r0, short* __restrict__ r1, short* __restrict__ r2) {
    int b = blockIdx.x;
    int rel = b / EG8;
    int i8 = (b - rel * EG8) * 256 + threadIdx.x;
    if (i8 >= NE / 8) return;
    const int* dst = (rel == 0) ? d0 : (rel == 1) ? d1 : d2;
    int* h = (rel == 0) ? h0 : (rel == 1) ? h1 : h2;
    short* rk = (rel == 0) ? r0 : (rel == 1) ? r1 : r2;
    int4 da = *((const int4*)dst + 2 * i8);
    int4 db = *((const int4*)dst + 2 * i8 + 1);
    union { short s[8]; int4 v; } u;
    u.s[0] = (short)atomicAdd(&h[da.x], 1);
    u.s[1] = (short)atomicAdd(&h[da.y], 1);
    u.s[2] = (short)atomicAdd(&h[da.z], 1);
    u.s[3] = (short)atomicAdd(&h[da.w], 1);
    u.s[4] = (short)atomicAdd(&h[db.x], 1);
    u.s[5] = (short)atomicAdd(&h[db.y], 1);
    u.s[6] = (short)atomicAdd(&h[db.z], 1);
    u.s[7] = (short)atomicAdd(&h[db.w], 1);
    *((int4*)rk + i8) = u.v;
}

// ---------------- scan phase A: per-chunk sums ----------------
__global__ __launch_bounds__(256) void scan_partial_kernel(const int* __restrict__ cur,
                                                           int* __restrict__ bsum) {
    int b = blockIdx.x, t = threadIdx.x;
    int4 v = *((const int4*)(cur + b * SCHUNK) + t);
    int s = v.x + v.y + v.z + v.w;
    __shared__ int sd[256];
    sd[t] = s;
    __syncthreads();
    for (int off = 128; off > 0; off >>= 1) {
        if (t < off) sd[t] += sd[t + off];
        __syncthreads();
    }
    if (t == 0) bsum[b] = sd[0];
}

// ---------------- scan phase B+C fused: each block redundantly scans bsum ---
__global__ __launch_bounds__(256) void scan_final_kernel(const int* __restrict__ cur,
        const int* __restrict__ bsum, int* __restrict__ rp0, int* __restrict__ rp1,
        int* __restrict__ rp2) {
    int b = blockIdx.x, t = threadIdx.x;
    __shared__ int sb[256];
    // inline phase B: exclusive chunk-offset via inclusive LDS scan of bsum
    int vb = (t < SNB) ? bsum[t] : 0;
    sb[t] = vb;
    __syncthreads();
    for (int off = 1; off < 256; off <<= 1) {
        int u = (t >= off) ? sb[t - off] : 0;
        __syncthreads();
        sb[t] += u;
        __syncthreads();
    }
    const int boffb = sb[b] - bsum[b];   // exclusive prefix for this chunk
    __syncthreads();
    // phase C: intra-chunk scan
    int base = b * SCHUNK + t * 4;
    int4 v = *(const int4*)(cur + base);
    int s = v.x + v.y + v.z + v.w;
    __shared__ int sd[256];
    sd[t] = s;
    __syncthreads();
    for (int off = 1; off < 256; off <<= 1) {
        int u = (t >= off) ? sd[t - off] : 0;
        __syncthreads();
        sd[t] += u;
        __syncthreads();
    }
    int pre = boffb + sd[t] - s;
    int ex[4];
    ex[0] = pre;
    ex[1] = ex[0] + v.x;
    ex[2] = ex[1] + v.y;
    ex[3] = ex[2] + v.z;
    #pragma unroll
    for (int i = 0; i < 4; i++) {
        int idx = base + i;
        if (idx < NTOT) {
            int* rp; int loc; int rbase;
            if (idx < NATTR)             { rp = rp0; loc = idx;                 rbase = 0; }
            else if (idx < NATTR + NAPP) { rp = rp1; loc = idx - NATTR;        rbase = NE; }
            else                         { rp = rp2; loc = idx - NATTR - NAPP; rbase = 2 * NE; }
            rp[loc] = ex[i] - rbase;
        }
    }
    if (b == 0 && t == 0) { rp0[NATTR] = NE; rp1[NAPP] = NE; rp2[NAPP] = NE; }
}

// ---------------- scatter, rank-based (NO atomics), 8 edges/thread ----------
__global__ __launch_bounds__(256) void scatter3_kernel(
        const int* __restrict__ s0, const int* __restrict__ d0, const float* __restrict__ e0,
        const short* __restrict__ r0, const int* __restrict__ rp0, int2* __restrict__ cw0,
        const int* __restrict__ s1, const int* __restrict__ d1, const float* __restrict__ e1,
        const short* __restrict__ r1, const int* __restrict__ rp1, int2* __restrict__ cw1,
        const int* __restrict__ s2, const int* __restrict__ d2, const float* __restrict__ e2,
        const short* __restrict__ r2, const int* __restrict__ rp2, int2* __restrict__ cw2) {
    int b = blockIdx.x;
    int rel = b / EG8;
    int i8 = (b - rel * EG8) * 256 + threadIdx.x;
    if (i8 >= NE / 8) return;
    const int* src; const int* dst; const float* ew; const short* rk; const int* rp; int2* cw;
    if (rel == 0)      { src = s0; dst = d0; ew = e0; rk = r0; rp = rp0; cw = cw0; }
    else if (rel == 1) { src = s1; dst = d1; ew = e1; rk = r1; rp = rp1; cw = cw1; }
    else               { src = s2; dst = d2; ew = e2; rk = r2; rp = rp2; cw = cw2; }
    int4 sa = *((const int4*)src + 2 * i8);
    int4 sb = *((const int4*)src + 2 * i8 + 1);
    int4 da = *((const int4*)dst + 2 * i8);
    int4 db = *((const int4*)dst + 2 * i8 + 1);
    float4 ea = *((const float4*)ew + 2 * i8);
    float4 eb = *((const float4*)ew + 2 * i8 + 1);
    union { short s[8]; int4 v; } u;
    u.v = *((const int4*)rk + i8);
    cw[rp[da.x] + u.s[0]] = make_int2(sa.x, __float_as_int(ea.x));
    cw[rp[da.y] + u.s[1]] = make_int2(sa.y, __float_as_int(ea.y));
    cw[rp[da.z] + u.s[2]] = make_int2(sa.z, __float_as_int(ea.z));
    cw[rp[da.w] + u.s[3]] = make_int2(sa.w, __float_as_int(ea.w));
    cw[rp[db.x] + u.s[4]] = make_int2(sb.x, __float_as_int(eb.x));
    cw[rp[db.y] + u.s[5]] = make_int2(sb.y, __float_as_int(eb.y));
    cw[rp[db.z] + u.s[6]] = make_int2(sb.z, __float_as_int(eb.z));
    cw[rp[db.w] + u.s[7]] = make_int2(sb.w, __float_as_int(eb.w));
}

// ---------------- pack weights + constants; blocks >=9 zero cur ------------
__global__ __launch_bounds__(256) void pack_kernel(
        const float* __restrict__ Wself1, const float* __restrict__ Wneigh1,
        const float* __restrict__ Wself2, const float* __restrict__ Wneigh2,
        const float* __restrict__ b1, const float* __restrict__ b2,
        const float* __restrict__ Wc, const float* __restrict__ bc,
        short* __restrict__ PBh, short* __restrict__ PBl,
        float* __restrict__ b1s, float* __restrict__ b2s,
        float* __restrict__ Cs, float* __restrict__ C1, float* __restrict__ C2,
        float* __restrict__ bconst, int* __restrict__ cur) {
    int m = blockIdx.x;
    if (m >= 9) {
        int idx = (m - 9) * 256 + threadIdx.x;
        const int n4 = (SNB * SCHUNK) / 4;
        for (int i = idx; i < n4; i += ZERO_B * 256)
            *((int4*)cur + i) = make_int4(0, 0, 0, 0);
        return;
    }
    if (m == 8) {
        int tid = threadIdx.x;
        int k = tid >> 1, j = tid & 1;
        const float* Wn1 = Wneigh2 + D * D;
        const float* Wn2 = Wneigh2 + 2 * D * D;
        const float* Ws1 = Wself2 + D * D;
        const float* Ws2 = Wself2 + 2 * D * D;
        float ss = 0.f, s1 = 0.f, s2 = 0.f;
        for (int tt = 0; tt < D; tt++) {
            float wc = Wc[tt * 2 + j];
            ss += (Ws1[k * D + tt] + Ws2[k * D + tt]) * wc;
            s1 += Wn1[k * D + tt] * wc;
            s2 += Wn2[k * D + tt] * wc;
        }
        Cs[tid] = ss; C1[tid] = s1; C2[tid] = s2;
        if (tid < 2) {
            float s = bc[tid];
            for (int tt = 0; tt < D; tt++)
                s += (b2[D + tt] + b2[2 * D + tt]) * Wc[tt * 2 + tid];
            bconst[tid] = s;
        }
        return;
    }
    const float* srcA; const float* srcB = nullptr;
    switch (m) {
        case 0: srcA = Wself1; break;
        case 1: srcA = Wneigh1; break;
        case 2: srcA = Wself1 + D * D; srcB = Wself1 + 2 * D * D; break;
        case 3: srcA = Wneigh1 + D * D; break;
        case 4: srcA = Wneigh1 + 2 * D * D; break;
        case 5: srcA = Wself2 + D * D; srcB = Wself2 + 2 * D * D; break;
        case 6: srcA = Wneigh2 + D * D; break;
        default: srcA = Wneigh2 + 2 * D * D; break;
    }
    short* oh = PBh + (size_t)m * D * D;
    short* ol = PBl + (size_t)m * D * D;
    for (int i = threadIdx.x; i < D * D; i += 256) {
        int k = i >> 7, n = i & 127;
        float v = srcA[i];
        if (srcB) v += srcB[i];
        short hi = bf16_rn(v);
        short lo = bf16_rn(v - bf16_to_f(hi));
        int kc = k >> 5, q = (k >> 3) & 3, j = k & 7, nt = n >> 4, c = n & 15;
        int pos = (((kc * 8 + nt) * 64) + q * 16 + c) * 8 + j;
        oh[pos] = hi;
        ol[pos] = lo;
    }
    if (m == 0 && threadIdx.x < D) {
        int t = threadIdx.x;
        b1s[t] = b1[D + t] + b1[2 * D + t];
        b2s[t] = b2[D + t] + b2[2 * D + t];
    }
}

// ---------------- fused gather + MFMA node update + collapsed classifier ----
// (round-8/9 verified body, unchanged: LDS edge staging with dummy clamp slot)
#define ASTR 128
template<int NG>
__device__ __forceinline__ void fused_body(
        const float* __restrict__ in0, const short* __restrict__ B0h, const short* __restrict__ B0l,
        const float* __restrict__ x1, const int* __restrict__ rp1, const int2* __restrict__ cw1,
        const short* __restrict__ B1h, const short* __restrict__ B1l,
        const float* __restrict__ x2, const int* __restrict__ rp2, const int2* __restrict__ cw2,
        const short* __restrict__ B2h, const short* __restrict__ B2l,
        const float* __restrict__ bias,
        const float* __restrict__ Ccol0, const float* __restrict__ Ccol1,
        float* __restrict__ zo0, float* __restrict__ zo1,
        int nrows, int row0, float* At, int2* eds) {
    const int t = threadIdx.x;
    const int w = t >> 6, lane = t & 63;
    const int q = lane >> 4, c = lane & 15;
    const int myrow = row0 + w * 16 + c;
    const int arow = min(myrow, nrows - 1);

    f32x4 acc[8];
    #pragma unroll
    for (int nt = 0; nt < 8; nt++) acc[nt] = (f32x4){0.f, 0.f, 0.f, 0.f};

    // ---- direct (self) source: global -> reg fragments ----
    {
        const float* __restrict__ arp = in0 + (size_t)arow * D;
        const bfrag* __restrict__ Bh = (const bfrag*)B0h;
        const bfrag* __restrict__ Bl = (const bfrag*)B0l;
        #pragma unroll
        for (int kc = 0; kc < 4; kc++) {
            float4 a0 = *(const float4*)(arp + kc * 32 + q * 8);
            float4 a1 = *(const float4*)(arp + kc * 32 + q * 8 + 4);
            union { unsigned u[4]; bfrag v; } ahu, alu;
            split2(a0.x, a0.y, ahu.u[0], alu.u[0]);
            split2(a0.z, a0.w, ahu.u[1], alu.u[1]);
            split2(a1.x, a1.y, ahu.u[2], alu.u[2]);
            split2(a1.z, a1.w, ahu.u[3], alu.u[3]);
            bfrag ah = ahu.v, al = alu.v;
            const bfrag* bh = Bh + kc * 512 + lane;
            const bfrag* bl = Bl + kc * 512 + lane;
            #pragma unroll
            for (int nt = 0; nt < 8; nt++) {
                bfrag vh = bh[nt * 64];
                bfrag vl = bl[nt * 64];
                acc[nt] = __builtin_amdgcn_mfma_f32_16x16x32_bf16(ah, vh, acc[nt], 0, 0, 0);
                acc[nt] = __builtin_amdgcn_mfma_f32_16x16x32_bf16(ah, vl, acc[nt], 0, 0, 0);
                acc[nt] = __builtin_amdgcn_mfma_f32_16x16x32_bf16(al, vh, acc[nt], 0, 0, 0);
            }
        }
    }

    // ---- gathered sources: stage edges -> LDS, gather -> LDS, MFMA ----
    const int grp = t >> 5, l32 = t & 31;
    #pragma unroll
    for (int g = 0; g < NG; g++) {
        const float* __restrict__ xs = (g == 0) ? x1 : x2;
        const int* __restrict__ rp   = (g == 0) ? rp1 : rp2;
        const int2* __restrict__ cw  = (g == 0) ? cw1 : cw2;
        const short* __restrict__ Bhp = (g == 0) ? B1h : B2h;
        const short* __restrict__ Blp = (g == 0) ? B1l : B2l;

        if (g > 0) __syncthreads();
        const int eb0 = rp[row0];
        const int eb1 = rp[min(row0 + 64, nrows)];
        const int ecnt = eb1 - eb0;
        const bool staged = (ecnt < ECAP);
        if (staged) {
            for (int i = t; i < ecnt; i += 256) eds[i] = cw[eb0 + i];
            if (t == 0) eds[ecnt] = make_int2(0, 0);
        }
        __syncthreads();

        {
            const int r0g = row0 + grp * 8;
            int bnd[9];
            #pragma unroll
            for (int i = 0; i < 9; i++) bnd[i] = rp[min(r0g + i, nrows)];
            #pragma unroll
            for (int p = 0; p < 4; p++) {
                const int A0 = bnd[2 * p],     A1 = bnd[2 * p + 1];
                const int B0 = bnd[2 * p + 1], B1 = bnd[2 * p + 2];
                float4 aA = make_float4(0.f, 0.f, 0.f, 0.f);
                float4 aB = make_float4(0.f, 0.f, 0.f, 0.f);
                const int lastA = min(max(A1 - 1, A0), NE - 1);
                const int lastB = min(max(B1 - 1, B0), NE - 1);
                int jA = A0, jB = B0;
                while (jA < A1 || jB < B1) {
                    int2 ed[8];
                    if (staged) {
                        #pragma unroll
                        for (int u = 0; u < 4; u++)
                            ed[u] = eds[min(min(jA + u, lastA) - eb0, ecnt)];
                        #pragma unroll
                        for (int u = 0; u < 4; u++)
                            ed[4 + u] = eds[min(min(jB + u, lastB) - eb0, ecnt)];
                    } else {
                        #pragma unroll
                        for (int u = 0; u < 4; u++) ed[u] = cw[min(jA + u, lastA)];
                        #pragma unroll
                        for (int u = 0; u < 4; u++) ed[4 + u] = cw[min(jB + u, lastB)];
                    }
                    float wt[8];
                    #pragma unroll
                    for (int u = 0; u < 4; u++)
                        wt[u] = (jA + u < A1) ? __int_as_float(ed[u].y) : 0.f;
                    #pragma unroll
                    for (int u = 0; u < 4; u++)
                        wt[4 + u] = (jB + u < B1) ? __int_as_float(ed[4 + u].y) : 0.f;
                    float4 v[8];
                    #pragma unroll
                    for (int u = 0; u < 8; u++)
                        v[u] = *(const float4*)(xs + (size_t)ed[u].x * D + l32 * 4);
                    aA.x += wt[0] * v[0].x + wt[1] * v[1].x + wt[2] * v[2].x + wt[3] * v[3].x;
                    aA.y += wt[0] * v[0].y + wt[1] * v[1].y + wt[2] * v[2].y + wt[3] * v[3].y;
                    aA.z += wt[0] * v[0].z + wt[1] * v[1].z + wt[2] * v[2].z + wt[3] * v[3].z;
                    aA.w += wt[0] * v[0].w + wt[1] * v[1].w + wt[2] * v[2].w + wt[3] * v[3].w;
                    aB.x += wt[4] * v[4].x + wt[5] * v[5].x + wt[6] * v[6].x + wt[7] * v[7].x;
                    aB.y += wt[4] * v[4].y + wt[5] * v[5].y + wt[6] * v[6].y + wt[7] * v[7].y;
                    aB.z += wt[4] * v[4].z + wt[5] * v[5].z + wt[6] * v[6].z + wt[7] * v[7].z;
                    aB.w += wt[4] * v[4].w + wt[5] * v[5].w + wt[6] * v[6].w + wt[7] * v[7].w;
                    jA += 4; jB += 4;
                }
                const float invA = 1.0f / (float)max(A1 - A0, 1);
                const float invB = 1.0f / (float)max(B1 - B0, 1);
                aA.x *= invA; aA.y *= invA; aA.z *= invA; aA.w *= invA;
                aB.x *= invB; aB.y *= invB; aB.z *= invB; aB.w *= invB;
                const int lrA = grp * 8 + 2 * p;
                const int lrB = lrA + 1;
                *(float4*)&At[lrA * ASTR + ((l32 ^ ((lrA & 3) << 1)) << 2)] = aA;
                *(float4*)&At[lrB * ASTR + ((l32 ^ ((lrB & 3) << 1)) << 2)] = aB;
            }
        }
        __syncthreads();

        const bfrag* __restrict__ Bh = (const bfrag*)Bhp;
        const bfrag* __restrict__ Bl = (const bfrag*)Blp;
        const int rloc = w * 16 + c;
        const int sw = (rloc & 3) << 1;
        const float* __restrict__ arow_lds = &At[rloc * ASTR];
        #pragma unroll
        for (int kc = 0; kc < 4; kc++) {
            const int g0 = kc * 8 + q * 2;
            float4 a0 = *(const float4*)(arow_lds + ((g0 ^ sw) << 2));
            float4 a1 = *(const float4*)(arow_lds + (((g0 + 1) ^ sw) << 2));
            union { unsigned u[4]; bfrag v; } ahu, alu;
            split2(a0.x, a0.y, ahu.u[0], alu.u[0]);
            split2(a0.z, a0.w, ahu.u[1], alu.u[1]);
            split2(a1.x, a1.y, ahu.u[2], alu.u[2]);
            split2(a1.z, a1.w, ahu.u[3], alu.u[3]);
            bfrag ah = ahu.v, al = alu.v;
            const bfrag* bh = Bh + kc * 512 + lane;
            const bfrag* bl = Bl + kc * 512 + lane;
            #pragma unroll
            for (int nt = 0; nt < 8; nt++) {
                bfrag vh = bh[nt * 64];
                bfrag vl = bl[nt * 64];
                acc[nt] = __builtin_amdgcn_mfma_f32_16x16x32_bf16(ah, vh, acc[nt], 0, 0, 0);
                acc[nt] = __builtin_amdgcn_mfma_f32_16x16x32_bf16(ah, vl, acc[nt], 0, 0, 0);
                acc[nt] = __builtin_amdgcn_mfma_f32_16x16x32_bf16(al, vh, acc[nt], 0, 0, 0);
            }
        }
    }

    // ---- epilogue: collapse h = relu(acc+bias) through C columns in-register.
    float c00[8], c01[8], c10[8], c11[8], bvv[8];
    #pragma unroll
    for (int nt = 0; nt < 8; nt++) {
        float2 v0 = *(const float2*)(Ccol0 + (nt * 16 + c) * 2);
        c00[nt] = v0.x; c01[nt] = v0.y;
        if (NG == 2) {
            float2 v1 = *(const float2*)(Ccol1 + (nt * 16 + c) * 2);
            c10[nt] = v1.x; c11[nt] = v1.y;
        }
        bvv[nt] = bias[nt * 16 + c];
    }
    #pragma unroll
    for (int r = 0; r < 4; r++) {
        int row = row0 + w * 16 + q * 4 + r;
        float s0 = 0.f, s1 = 0.f, t0 = 0.f, t1 = 0.f;
        #pragma unroll
        for (int nt = 0; nt < 8; nt++) {
            float h = fmaxf(acc[nt][r] + bvv[nt], 0.f);
            s0 += h * c00[nt]; s1 += h * c01[nt];
            if (NG == 2) { t0 += h * c10[nt]; t1 += h * c11[nt]; }
        }
        #pragma unroll
        for (int off = 1; off < 16; off <<= 1) {
            s0 += __shfl_xor(s0, off);
            s1 += __shfl_xor(s1, off);
            if (NG == 2) { t0 += __shfl_xor(t0, off); t1 += __shfl_xor(t1, off); }
        }
        if (c == 0 && row < nrows) {
            *(float2*)(zo0 + (size_t)row * 2) = make_float2(s0, s1);
            if (NG == 2) *(float2*)(zo1 + (size_t)row * 2) = make_float2(t0, t1);
        }
    }
}

__global__ __launch_bounds__(256, 4) void fused_all_kernel(
        const float* __restrict__ xapp, const float* __restrict__ xattr,
        const short* __restrict__ PBh, const short* __restrict__ PBl,
        const int* __restrict__ rp0, const int2* __restrict__ cw0,
        const int* __restrict__ rp1, const int2* __restrict__ cw1,
        const int* __restrict__ rp2, const int2* __restrict__ cw2,
        const float* __restrict__ b1, const float* __restrict__ b1s,
        const float* __restrict__ Cs, const float* __restrict__ C2,
        const float* __restrict__ C1,
        float* __restrict__ zs, float* __restrict__ z2, float* __restrict__ za) {
    __shared__ __align__(16) float At[64 * ASTR];
    __shared__ __align__(16) int2 eds[ECAP];
    const size_t MM = (size_t)D * D;
    int b = blockIdx.x;
    if (b < GB_APP) {
        fused_body<2>(xapp, PBh + 2 * MM, PBl + 2 * MM,
                      xattr, rp1, cw1, PBh + 3 * MM, PBl + 3 * MM,
                      xapp,  rp2, cw2, PBh + 4 * MM, PBl + 4 * MM,
                      b1s, Cs, C2, zs, z2, NAPP, b * 64, At, eds);
    } else {
        int bb = b - GB_APP;
        fused_body<1>(xattr, PBh, PBl,
                      xapp, rp0, cw0, PBh + 1 * MM, PBl + 1 * MM,
                      nullptr, nullptr, nullptr, nullptr, nullptr,
                      b1, C1, nullptr, za, nullptr, NATTR, bb * 64, At, eds);
    }
}

// ---------------- final: 4 lanes/row ----------------------------------------
__global__ __launch_bounds__(256) void final_out_kernel(
        const float* __restrict__ zs, const float* __restrict__ za,
        const float* __restrict__ z2,
        const int* __restrict__ rp1, const int2* __restrict__ cw1,
        const int* __restrict__ rp2, const int2* __restrict__ cw2,
        const float* __restrict__ bconst, float* __restrict__ out, int n) {
    int r = (blockIdx.x * 256 + threadIdx.x) >> 2;
    int l = threadIdx.x & 3;
    if (r >= n) return;
    int s0 = rp1[r], s1 = rp1[r + 1];
    float q0 = 0.f, q1 = 0.f;
    for (int j = s0 + l; j < s1; j += 4) {
        int2 e = cw1[j];
        float w = __int_as_float(e.y);
        float2 v = *(const float2*)(za + (size_t)e.x * 2);
        q0 += w * v.x; q1 += w * v.y;
    }
    float inv1 = 1.0f / (float)max(s1 - s0, 1);
    float p0 = q0 * inv1, p1 = q1 * inv1;
    s0 = rp2[r]; s1 = rp2[r + 1];
    q0 = 0.f; q1 = 0.f;
    for (int j = s0 + l; j < s1; j += 4) {
        int2 e = cw2[j];
        float w = __int_as_float(e.y);
        float2 v = *(const float2*)(z2 + (size_t)e.x * 2);
        q0 += w * v.x; q1 += w * v.y;
    }
    float inv2 = 1.0f / (float)max(s1 - s0, 1);
    p0 += q0 * inv2; p1 += q1 * inv2;
    #pragma unroll
    for (int off = 1; off < 4; off <<= 1) {
        p0 += __shfl_xor(p0, off);
        p1 += __shfl_xor(p1, off);
    }
    if (l == 0) {
        float2 s = *(const float2*)(zs + (size_t)r * 2);
        out[(size_t)r * 2 + 0] = p0 + s.x + bconst[0];
        out[(size_t)r * 2 + 1] = p1 + s.y + bconst[1];
    }
}

extern "C" void kernel_launch(void* const* d_in, const int* in_sizes, int n_in,
                              void* d_out, int out_size, void* d_ws, size_t ws_size,
                              hipStream_t stream) {
    const float* x_app   = (const float*)d_in[0];
    const float* x_attr  = (const float*)d_in[1];
    const float* ew0     = (const float*)d_in[2];
    const float* ew1     = (const float*)d_in[3];
    const float* ew2     = (const float*)d_in[4];
    const float* Wself1  = (const float*)d_in[5];
    const float* Wneigh1 = (const float*)d_in[6];
    const float* b1      = (const float*)d_in[7];
    const float* Wself2  = (const float*)d_in[8];
    const float* Wneigh2 = (const float*)d_in[9];
    const float* b2      = (const float*)d_in[10];
    const float* Wc      = (const float*)d_in[11];
    const float* bc      = (const float*)d_in[12];
    const int* src0 = (const int*)d_in[13];
    const int* dst0 = (const int*)d_in[14];
    const int* src1 = (const int*)d_in[15];
    const int* dst1 = (const int*)d_in[16];
    const int* src2 = (const int*)d_in[17];
    const int* dst2 = (const int*)d_in[18];
    float* out = (float*)d_out;

    // ---- workspace layout (4-byte units; cw blocks start at even offsets) ----
    float* ws = (float*)d_ws;
    float* h_attr = ws;                                  // NATTR*D (reused: ranks)
    float* h_app  = h_attr + (size_t)NATTR * D;          // NAPP*D (unused)
    float* b1s    = h_app  + (size_t)NAPP * D;           // D
    float* b2s    = b1s + D;                             // D
    float* za     = b2s + D;                             // NATTR*2
    float* zsv    = za + (size_t)NATTR * 2;              // NAPP*2
    float* z2v    = zsv + (size_t)NAPP * 2;              // NAPP*2
    float* Cs     = z2v + (size_t)NAPP * 2;              // 256
    float* C1     = Cs + 256;                            // 256
    float* C2     = C1 + 256;                            // 256
    float* bconst = C2 + 256;                            // 4
    int* cur  = (int*)(bconst + 4);                      // SNB*SCHUNK
    int* cur0 = cur;
    int* cur1 = cur0 + NATTR;
    int* cur2 = cur1 + NAPP;
    int* rp0  = cur + SNB * SCHUNK;                      // NATTR+4
    int* rp1  = rp0 + NATTR + 4;                         // NAPP+4
    int* rp2  = rp1 + NAPP + 4;                          // NAPP+4
    int* bsum = rp2 + NAPP + 4;                          // 256
    int* boff = bsum + 256;                              // 256 (unused now)
    int2* cw0 = (int2*)(boff + 256);                     // NE int2
    int2* cw1 = cw0 + NE;                                // NE int2
    int2* cw2 = cw1 + NE;                                // NE int2
    short* PBh = (short*)(cw2 + NE);                     // 8*D*D shorts
    short* PBl = PBh + (size_t)8 * D * D;                // 8*D*D shorts
    // rank arrays (short) live in the dead h_attr slot (3 MB << 25.6 MB)
    short* rank0 = (short*)h_attr;                       // NE shorts
    short* rank1 = rank0 + NE;                           // NE shorts
    short* rank2 = rank1 + NE;                           // NE shorts

    // ---- pack weights + zero cur (blocks >=9), one launch ----
    pack_kernel<<<9 + ZERO_B, 256, 0, stream>>>(Wself1, Wneigh1, Wself2, Wneigh2,
                                                b1, b2, Wc, bc, PBh, PBl, b1s, b2s,
                                                Cs, C1, C2, bconst, cur);

    // ---- CSR build (rank-recording; scatter is atomic-free) ----
    hist3_kernel<<<3 * EG8, 256, 0, stream>>>(dst0, dst1, dst2, cur0, cur1, cur2,
                                              rank0, rank1, rank2);
    scan_partial_kernel<<<SNB, 256, 0, stream>>>(cur, bsum);
    scan_final_kernel<<<SNB, 256, 0, stream>>>(cur, bsum, rp0, rp1, rp2);
    scatter3_kernel<<<3 * EG8, 256, 0, stream>>>(
        src0, dst0, ew0, rank0, rp0, cw0,
        src1, dst1, ew1, rank1, rp1, cw1,
        src2, dst2, ew2, rank2, rp2, cw2);

    // ---- layer 1 + collapsed layer-2 projections, one launch ----
    fused_all_kernel<<<GB_APP + GB_ATTR, 256, 0, stream>>>(
        x_app, x_attr, PBh, PBl,
        rp0, cw0, rp1, cw1, rp2, cw2,
        b1, b1s, Cs, C2, C1, zsv, z2v, za);

    // ---- final gather over collapsed 2-wide features ----
    final_out_kernel<<<((size_t)NAPP * 4 + 255) / 256, 256, 0, stream>>>(
        zsv, za, z2v, rp1, cw1, rp2, cw2, bconst, out, NAPP);
}